// Round 9
// baseline (102.334 us; speedup 1.0000x reference)
//
#include <hip/hip_runtime.h>
#include <cstddef>

#define B_  2
#define N_  2048
#define L_  5
#define HH  8
#define P_  4
#define S_  21824
#define DQK 32

using bf16x8 = __attribute__((ext_vector_type(8))) short;
using f32x4  = __attribute__((ext_vector_type(4))) float;
using us8    = __attribute__((ext_vector_type(8))) unsigned short;

__device__ __forceinline__ unsigned short f2b(float f) {
  unsigned u = __builtin_bit_cast(unsigned, f);
  u += 0x7FFFu + ((u >> 16) & 1u);            // round-to-nearest-even
  return (unsigned short)(u >> 16);
}
__device__ __forceinline__ float b2f(unsigned short h) {
  return __builtin_bit_cast(float, ((unsigned)h) << 16);
}
// packed f32x2 -> bf16x2 (RNE), single VALU op
__device__ __forceinline__ unsigned cvtpk(float lo, float hi) {
  unsigned r;
  asm("v_cvt_pk_bf16_f32 %0, %1, %2" : "=v"(r) : "v"(lo), "v"(hi));
  return r;
}

__device__ __forceinline__ void gld_lds16(const void* g, void* l) {
  __builtin_amdgcn_global_load_lds(
      (const __attribute__((address_space(1))) unsigned int*)g,
      (__attribute__((address_space(3))) unsigned int*)l, 16, 0, 0);
}

// DPP-based add: v += permuted(v). VALU pipe, no LDS round-trip.
template <int CTRL>
__device__ __forceinline__ float dppadd(float v) {
  const int x = __builtin_bit_cast(int, v);
  return v + __builtin_bit_cast(float,
      __builtin_amdgcn_update_dpp(x, x, CTRL, 0xF, 0xF, false));
}

// ---------------------------------------------------------------------------
// cvt_all: small tensors only (sfeats converts inside the kv GEMM).
// ---------------------------------------------------------------------------
#define F0 131072   // in_feats -> if_hi + if_lo   (4096*256/8)
#define F1 147456   // + W_kv -> wkv_bf            (512*256/8)
#define F2 155648   // + W_q  -> wq_bf             (256*256/8)
#define F3 163840   // + W_out -> wout_bf          (256*256/8)
#define F4 176128   // + W_off(pad384) -> woff_hi  (384*256/8)
#define F5 188416   // + W_off(pad384) -> woff_lo  (384*256/8)

__device__ __forceinline__ void cvt8_plain(const float* s, unsigned short* d, int u) {
  const float4 a = ((const float4*)s)[2 * u];
  const float4 b = ((const float4*)s)[2 * u + 1];
  us8 o;
  o[0] = f2b(a.x); o[1] = f2b(a.y); o[2] = f2b(a.z); o[3] = f2b(a.w);
  o[4] = f2b(b.x); o[5] = f2b(b.y); o[6] = f2b(b.z); o[7] = f2b(b.w);
  ((us8*)d)[u] = o;
}
__device__ __forceinline__ unsigned short f2b_lo(float x) {
  return f2b(x - b2f(f2b(x)));
}
__device__ __forceinline__ void cvt8_lo(const float* s, unsigned short* d, int u) {
  const float4 a = ((const float4*)s)[2 * u];
  const float4 b = ((const float4*)s)[2 * u + 1];
  us8 o;
  o[0] = f2b_lo(a.x); o[1] = f2b_lo(a.y); o[2] = f2b_lo(a.z); o[3] = f2b_lo(a.w);
  o[4] = f2b_lo(b.x); o[5] = f2b_lo(b.y); o[6] = f2b_lo(b.z); o[7] = f2b_lo(b.w);
  ((us8*)d)[u] = o;
}
__device__ __forceinline__ void cvt8_both(const float* s, unsigned short* dh,
                                          unsigned short* dl, int u) {
  const float4 a = ((const float4*)s)[2 * u];
  const float4 b = ((const float4*)s)[2 * u + 1];
  us8 oh, ol;
  const float v[8] = {a.x, a.y, a.z, a.w, b.x, b.y, b.z, b.w};
#pragma unroll
  for (int k = 0; k < 8; ++k) {
    const unsigned short h = f2b(v[k]);
    oh[k] = h;
    ol[k] = f2b(v[k] - b2f(h));
  }
  ((us8*)dh)[u] = oh;
  ((us8*)dl)[u] = ol;
}

__global__ __launch_bounds__(256) void cvt_all(
    const float* __restrict__ in_feats, const float* __restrict__ W_kv,
    const float* __restrict__ W_q, const float* __restrict__ W_out,
    const float* __restrict__ W_off,
    unsigned short* __restrict__ if_hi, unsigned short* __restrict__ if_lo,
    unsigned short* __restrict__ wkv_bf, unsigned short* __restrict__ wq_bf,
    unsigned short* __restrict__ wout_bf, unsigned short* __restrict__ woff_hi,
    unsigned short* __restrict__ woff_lo) {
  const int i = blockIdx.x * 256 + threadIdx.x;
  if      (i < F0) cvt8_both(in_feats, if_hi, if_lo, i);
  else if (i < F1) cvt8_plain(W_kv, wkv_bf, i - F0);
  else if (i < F2) cvt8_plain(W_q, wq_bf, i - F1);
  else if (i < F3) cvt8_plain(W_out, wout_bf, i - F2);
  else if (i < F4) {
    const int u = i - F3;
    if ((u >> 5) < 320) cvt8_plain(W_off, woff_hi, u);
    else ((us8*)woff_hi)[u] = (us8)0;
  } else {
    const int u = i - F4;
    if ((u >> 5) < 320) cvt8_lo(W_off, woff_lo, u);
    else ((us8*)woff_lo)[u] = (us8)0;
  }
}

// ---------------------------------------------------------------------------
// Classic staged MFMA tile (128x128, BK=64) for off/q/out. 2 barriers/K-step.
// ---------------------------------------------------------------------------
__device__ __forceinline__ void mfma_compute(
    const unsigned short* As, const unsigned short* Bs,
    int wr, int wc, int fr, int fq, f32x4 (&acc)[4][4]) {
#pragma unroll
  for (int kk = 0; kk < 2; ++kk) {
    bf16x8 af[4], bfv[4];
#pragma unroll
    for (int i = 0; i < 4; ++i) {
      const int ar = wr * 64 + i * 16 + fr;
      const int cha = (kk * 4 + fq) ^ (ar & 7);
      af[i] = *(const bf16x8*)(As + ar * 64 + cha * 8);
      const int br = wc * 64 + i * 16 + fr;
      const int chb = (kk * 4 + fq) ^ (br & 7);
      bfv[i] = *(const bf16x8*)(Bs + br * 64 + chb * 8);
    }
#pragma unroll
    for (int i = 0; i < 4; ++i)
#pragma unroll
      for (int j = 0; j < 4; ++j)
        acc[i][j] = __builtin_amdgcn_mfma_f32_16x16x32_bf16(
            af[i], bfv[j], acc[i][j], 0, 0, 0);
  }
}

__device__ __forceinline__ void mfma_tile_bf16(
    const unsigned short* __restrict__ Ap, const unsigned short* __restrict__ Wp,
    unsigned short* As, unsigned short* Bs,
    int row0, int col0, int wv, int wr, int wc, int fr, int fq,
    int srow, int sch, f32x4 (&acc)[4][4]) {
  for (int k0 = 0; k0 < 256; k0 += 64) {
#pragma unroll
    for (int i = 0; i < 4; ++i) {
      const int r = i * 32 + srow;
      const int ca = sch ^ (r & 7);
      gld_lds16(Ap + (size_t)(row0 + r) * 256 + k0 + ca * 8,
                As + (size_t)(i * 32 + wv * 8) * 64);
      gld_lds16(Wp + (size_t)(col0 + r) * 256 + k0 + ca * 8,
                Bs + (size_t)(i * 32 + wv * 8) * 64);
    }
    __syncthreads();
    mfma_compute(As, Bs, wr, wc, fr, fq, acc);
    __syncthreads();
  }
}

// ---------------------------------------------------------------------------
// Ubergemm: off [0,96) | q [96,160) | kv [160,1536).
// kv path: W-strip [128 x K=256] staged in LDS ONCE (single barrier),
// XOR-swizzled; A streamed f32 global -> cvt_pk -> MFMA regs (no LDS, no
// barriers in the K-loop). kv blocks XCD-grouped: the 4 column-blocks of an
// A-row-panel land on one XCD (bx%8 bijective decode) for L2 reuse of A.
// ---------------------------------------------------------------------------
__global__ __launch_bounds__(256) void ubergemm(
    const float* __restrict__ sfeats,
    const unsigned short* __restrict__ wkv_bf,
    const unsigned short* __restrict__ if_hi,
    const unsigned short* __restrict__ if_lo,
    const unsigned short* __restrict__ woff_hi,
    const unsigned short* __restrict__ woff_lo,
    const unsigned short* __restrict__ wq_bf,
    const float* __restrict__ b_kv, const float* __restrict__ b_off,
    const float* __restrict__ b_q,
    unsigned short* __restrict__ kvt, float* __restrict__ offb,
    float* __restrict__ qb) {
  __shared__ __align__(16) unsigned short lds[128 * 256];   // 64 KB

  const int tid = threadIdx.x;
  const int lane = tid & 63;
  const int wv = tid >> 6;
  const int wr = wv >> 1, wc = wv & 1;
  const int fr = lane & 15, fq = lane >> 4;
  const int bx = blockIdx.x;

  f32x4 acc[4][4] = {};

  if (bx >= 160) {          // ---- kv path ----
    const int t = bx - 160;
    const int x = t & 7;            // XCD slot
    const int idx = t >> 3;
    const int c = idx & 3;          // column block 0..3
    const int gi = idx >> 2;
    const int g = gi * 8 + x;       // row panel 0..340
    if (g >= 341) return;
    const int row0 = g * 128;
    const int col0 = c * 128;

    // Stage W-strip [128][256] bf16 into LDS once, chunk-swizzled.
    // chunk index ci = s*256 + tid; n = ci>>5 (row), cc = ci&31 (16B chunk).
#pragma unroll
    for (int s = 0; s < 16; ++s) {
      const int ci = s * 256 + tid;
      const int n = ci >> 5, cc = ci & 31;
      gld_lds16(wkv_bf + (size_t)(col0 + n) * 256 + (cc ^ (n & 7)) * 8,
                lds + (s * 256 + wv * 64) * 8);
    }
    __syncthreads();   // only barrier in the kv path

#pragma unroll 2
    for (int kk = 0; kk < 8; ++kk) {
      bf16x8 af[4], bfv[4];
#pragma unroll
      for (int i = 0; i < 4; ++i) {
        const float* ap = sfeats +
            (size_t)(row0 + wr * 64 + i * 16 + fr) * 256 + kk * 32 + fq * 8;
        const float4 a0 = *(const float4*)ap;
        const float4 a1 = *(const float4*)(ap + 4);
        uint4 u;
        u.x = cvtpk(a0.x, a0.y);
        u.y = cvtpk(a0.z, a0.w);
        u.z = cvtpk(a1.x, a1.y);
        u.w = cvtpk(a1.z, a1.w);
        af[i] = __builtin_bit_cast(bf16x8, u);
      }
#pragma unroll
      for (int j = 0; j < 4; ++j) {
        const int n = wc * 64 + j * 16 + fr;
        const int ch = (kk * 4 + fq) ^ (n & 7);
        bfv[j] = *(const bf16x8*)(lds + (n * 32 + ch) * 8);
      }
#pragma unroll
      for (int i = 0; i < 4; ++i)
#pragma unroll
        for (int j = 0; j < 4; ++j)
          acc[i][j] = __builtin_amdgcn_mfma_f32_16x16x32_bf16(
              af[i], bfv[j], acc[i][j], 0, 0, 0);
    }

    // epilogue: kv layout store, bf16
#pragma unroll
    for (int j = 0; j < 4; ++j) {
      const int n = col0 + wc * 64 + j * 16 + fr;
      const float bv = b_kv[n];
      const int h = n >> 6, cch = n & 63;
#pragma unroll
      for (int i = 0; i < 4; ++i) {
        const int mbase = row0 + wr * 64 + i * 16 + fq * 4;
#pragma unroll
        for (int r = 0; r < 4; ++r) {
          const int m = mbase + r;
          const int b = (m >= S_) ? 1 : 0;
          const int s = m - b * S_;
          kvt[((size_t)(b * HH + h) * S_ + s) * 64 + cch] = f2b(acc[i][j][r] + bv);
        }
      }
    }
    return;
  }

  // ---- off / q paths (classic staged tiles) ----
  unsigned short* As = lds;
  unsigned short* Bs = lds + 128 * 64;
  const int srow = tid >> 3;
  const int sch = tid & 7;
  int row0, col0, ldc, nbias;
  const float* bias;
  float* Cf;
  if (bx < 96) {            // off: 3 K-segments, bf16x3
    col0 = (bx % 3) * 128; row0 = (bx / 3) * 128;
    bias = b_off; Cf = offb; ldc = 384; nbias = 320;
    mfma_tile_bf16(if_hi, woff_hi, As, Bs, row0, col0, wv, wr, wc, fr, fq, srow, sch, acc);
    mfma_tile_bf16(if_hi, woff_lo, As, Bs, row0, col0, wv, wr, wc, fr, fq, srow, sch, acc);
    mfma_tile_bf16(if_lo, woff_hi, As, Bs, row0, col0, wv, wr, wc, fr, fq, srow, sch, acc);
  } else {                  // q
    const int t = bx - 96;
    col0 = (t & 1) * 128; row0 = (t >> 1) * 128;
    bias = b_q; Cf = qb; ldc = 256; nbias = 256;
    mfma_tile_bf16(if_hi, wq_bf, As, Bs, row0, col0, wv, wr, wc, fr, fq, srow, sch, acc);
  }

#pragma unroll
  for (int j = 0; j < 4; ++j) {
    const int n = col0 + wc * 64 + j * 16 + fr;
    const float bv = (n < nbias) ? bias[n] : 0.f;
#pragma unroll
    for (int i = 0; i < 4; ++i) {
      const int mbase = row0 + wr * 64 + i * 16 + fq * 4;
#pragma unroll
      for (int r = 0; r < 4; ++r)
        Cf[(size_t)(mbase + r) * ldc + n] = acc[i][j][r] + bv;
    }
  }
}

// ---------------------------------------------------------------------------
// out-projection GEMM: bf16 MFMA, f32 out.
// ---------------------------------------------------------------------------
__global__ __launch_bounds__(256) void gemm_out(
    const unsigned short* __restrict__ A, const unsigned short* __restrict__ Wt,
    const float* __restrict__ bias, float* __restrict__ C) {
  __shared__ __align__(16) unsigned short As[128 * 64];
  __shared__ __align__(16) unsigned short Bs[128 * 64];
  const int tid = threadIdx.x;
  const int lane = tid & 63;
  const int wv = tid >> 6;
  const int wr = wv >> 1, wc = wv & 1;
  const int fr = lane & 15, fq = lane >> 4;
  const int row0 = blockIdx.y * 128, col0 = blockIdx.x * 128;
  const int srow = tid >> 3, sch = tid & 7;
  f32x4 acc[4][4] = {};
  mfma_tile_bf16(A, Wt, As, Bs, row0, col0, wv, wr, wc, fr, fq, srow, sch, acc);
#pragma unroll
  for (int j = 0; j < 4; ++j) {
    const int n = col0 + wc * 64 + j * 16 + fr;
    const float bv = bias[n];
#pragma unroll
    for (int i = 0; i < 4; ++i) {
      const int mbase = row0 + wr * 64 + i * 16 + fq * 4;
#pragma unroll
      for (int r = 0; r < 4; ++r)
        C[(size_t)(mbase + r) * 256 + n] = acc[i][j][r] + bv;
    }
  }
}

// ---------------------------------------------------------------------------
// sample_attn4: XCD-partitioned slices; DPP reduce; 1-deep gather prefetch.
// ---------------------------------------------------------------------------
__global__ __launch_bounds__(256) void sample_attn4(
    const unsigned short* __restrict__ kvt, // [B*HH, S, 64] bf16
    const float* __restrict__ offb,         // [B*N, 384]
    const float* __restrict__ qb,           // [B*N, 256]
    const float* __restrict__ priors,       // [B, N, L, 2]
    const int* __restrict__ shapes,         // [L, 2] (H, W)
    const int* __restrict__ starts,         // [L]
    const float* __restrict__ pencs,        // [HH, 20, 32]
    unsigned short* __restrict__ wtd) {     // [B*N, 256] bf16
  __shared__ __align__(16) int pbuf[4][20][8];
  const int wv = threadIdx.x >> 6;
  const int lane = threadIdx.x & 63;
  const int beta = blockIdx.x;
  const int sig = (beta & 7) * 2 + ((beta >> 3) & 1);  // slice 0..15
  const int chunk = beta >> 4;                          // 0..511
  const int h = sig & 7;
  const int b = sig >> 3;
  const int bn = b * N_ + chunk * 4 + wv;
  const int j = lane & 31;
  const int half = lane >> 5;

  if (lane < 20) {
    const int pp = lane;
    const int l = pp >> 2;
    const float2 oxy = *(const float2*)(offb + (size_t)bn * 384 + h * 40 + pp * 2);
    const float2 pxy = *(const float2*)(priors + ((size_t)bn * 5 + l) * 2);
    const int Wd = shapes[l * 2 + 1];
    const int Hd = shapes[l * 2 + 0];
    const int st = starts[l];
    const float Wf = (float)Wd, Hf = (float)Hd;
    const float x = (pxy.x + oxy.x / Wf) * Wf - 0.5f;
    const float y = (pxy.y + oxy.y / Hf) * Hf - 0.5f;
    const float x0f = floorf(x), y0f = floorf(y);
    const float fx = x - x0f, fy = y - y0f;
    const int xi = (int)x0f, yi = (int)y0f;
    int a[4]; float w[4];
#pragma unroll
    for (int dy = 0; dy < 2; ++dy)
#pragma unroll
      for (int dx = 0; dx < 2; ++dx) {
        const int xc = xi + dx, yc = yi + dy;
        const bool valid = (xc >= 0) & (xc < Wd) & (yc >= 0) & (yc < Hd);
        const float wt = (dx ? fx : 1.f - fx) * (dy ? fy : 1.f - fy);
        const int xcc = min(max(xc, 0), Wd - 1);
        const int ycc = min(max(yc, 0), Hd - 1);
        a[dy * 2 + dx] = (st + ycc * Wd + xcc) * 32;
        w[dy * 2 + dx] = valid ? wt : 0.f;
      }
    *(int4*)&pbuf[wv][pp][0] = make_int4(a[0], a[1], a[2], a[3]);
    *(float4*)&pbuf[wv][pp][4] = make_float4(w[0], w[1], w[2], w[3]);
  }

  const int jc = j & 15;
  float2 q2 = *(const float2*)(qb + (size_t)bn * 256 + h * DQK + 2 * jc);
  q2.x *= 0.17677669529663687f;
  q2.y *= 0.17677669529663687f;
  float qpe[10];
#pragma unroll
  for (int i = 0; i < 10; ++i) {
    const float2 pe = *(const float2*)(
        pencs + ((size_t)h * 20 + 2 * i + half) * DQK + 2 * jc);
    qpe[i] = q2.x * pe.x + q2.y * pe.y;
  }

  const unsigned* kvd = (const unsigned*)(kvt + (size_t)(b * HH + h) * (S_ * 64));
  int4 aa[2]; float4 ww[2]; unsigned g[2][4];
  aa[0] = *(const int4*)&pbuf[wv][half][0];
  ww[0] = *(const float4*)&pbuf[wv][half][4];
  g[0][0] = kvd[(unsigned)aa[0].x + j];
  g[0][1] = kvd[(unsigned)aa[0].y + j];
  g[0][2] = kvd[(unsigned)aa[0].z + j];
  g[0][3] = kvd[(unsigned)aa[0].w + j];

  float2 sam[10];
  float lg[10];
#pragma unroll
  for (int i = 0; i < 10; ++i) {
    const int cur = i & 1, nxt = cur ^ 1;
    if (i < 9) {
      aa[nxt] = *(const int4*)&pbuf[wv][2 * (i + 1) + half][0];
      ww[nxt] = *(const float4*)&pbuf[wv][2 * (i + 1) + half][4];
      g[nxt][0] = kvd[(unsigned)aa[nxt].x + j];
      g[nxt][1] = kvd[(unsigned)aa[nxt].y + j];
      g[nxt][2] = kvd[(unsigned)aa[nxt].z + j];
      g[nxt][3] = kvd[(unsigned)aa[nxt].w + j];
    }
    const float4 wt = ww[cur];
    const unsigned g0 = g[cur][0], g1 = g[cur][1], g2 = g[cur][2], g3 = g[cur][3];
    const float lo0 = __builtin_bit_cast(float, g0 << 16);
    const float hi0 = __builtin_bit_cast(float, g0 & 0xFFFF0000u);
    const float lo1 = __builtin_bit_cast(float, g1 << 16);
    const float hi1 = __builtin_bit_cast(float, g1 & 0xFFFF0000u);
    const float lo2 = __builtin_bit_cast(float, g2 << 16);
    const float hi2 = __builtin_bit_cast(float, g2 & 0xFFFF0000u);
    const float lo3 = __builtin_bit_cast(float, g3 << 16);
    const float hi3 = __builtin_bit_cast(float, g3 & 0xFFFF0000u);
    float vx = wt.x * lo0;  vx = fmaf(wt.y, lo1, vx);
    vx = fmaf(wt.z, lo2, vx); vx = fmaf(wt.w, lo3, vx);
    float vy = wt.x * hi0;  vy = fmaf(wt.y, hi1, vy);
    vy = fmaf(wt.z, hi2, vy); vy = fmaf(wt.w, hi3, vy);
    sam[i].x = vx; sam[i].y = vy;
    float part = (j < 16) ? fmaf(q2.x, vx, fmaf(q2.y, vy, qpe[i])) : 0.f;
    part = dppadd<0xB1>(part);    // quad_perm xor1
    part = dppadd<0x4E>(part);    // quad_perm xor2
    part = dppadd<0x124>(part);   // row_ror:4
    part = dppadd<0x128>(part);   // row_ror:8 -> row16 sum
    lg[i] = part + __shfl_xor(part, 16, 64);
  }

  float mx = lg[0];
#pragma unroll
  for (int i = 1; i < 10; ++i) mx = fmaxf(mx, lg[i]);
  mx = fmaxf(mx, __shfl_xor(mx, 32, 64));
  float se = 0.f;
#pragma unroll
  for (int i = 0; i < 10; ++i) {
    lg[i] = __expf(lg[i] - mx);
    se += lg[i];
  }
  se += __shfl_xor(se, 32, 64);
  const float inv = 1.f / se;

  float ax = 0.f, ay = 0.f;
#pragma unroll
  for (int i = 0; i < 10; ++i) {
    ax = fmaf(lg[i], sam[i].x, ax);
    ay = fmaf(lg[i], sam[i].y, ay);
  }
  ax += __shfl_xor(ax, 32, 64);
  ay += __shfl_xor(ay, 32, 64);

  if (half == 0 && j >= 16) {
    const unsigned u = (unsigned)f2b(ax * inv) | ((unsigned)f2b(ay * inv) << 16);
    ((unsigned*)wtd)[(size_t)bn * 128 + h * 16 + (j - 16)] = u;
  }
}

// ---------------------------------------------------------------------------
extern "C" void kernel_launch(void* const* d_in, const int* in_sizes, int n_in,
                              void* d_out, int out_size, void* d_ws, size_t ws_size,
                              hipStream_t stream) {
  const float* in_feats = (const float*)d_in[0];
  const float* priors   = (const float*)d_in[1];
  const float* sfeats   = (const float*)d_in[2];
  const int*   shapes   = (const int*)d_in[3];
  const int*   starts   = (const int*)d_in[4];
  const float* W_off    = (const float*)d_in[5];
  const float* b_off    = (const float*)d_in[6];
  const float* W_q      = (const float*)d_in[7];
  const float* b_q      = (const float*)d_in[8];
  const float* W_kv     = (const float*)d_in[9];
  const float* b_kv     = (const float*)d_in[10];
  const float* pencs    = (const float*)d_in[11];
  const float* W_out    = (const float*)d_in[12];
  const float* b_out    = (const float*)d_in[13];
  float* out = (float*)d_out;

  char* w = (char*)d_ws;
  unsigned short* kvt = (unsigned short*)w;            // 44.7 MB
  w += (size_t)B_ * HH * S_ * 64 * 2;
  unsigned short* if_hi = (unsigned short*)w; w += (size_t)4096 * 256 * 2;
  unsigned short* if_lo = (unsigned short*)w; w += (size_t)4096 * 256 * 2;
  unsigned short* wkv_bf = (unsigned short*)w;  w += (size_t)512 * 256 * 2;
  unsigned short* wq_bf  = (unsigned short*)w;  w += (size_t)256 * 256 * 2;
  unsigned short* wout_bf = (unsigned short*)w; w += (size_t)256 * 256 * 2;
  unsigned short* woff_hi = (unsigned short*)w; w += (size_t)384 * 256 * 2;
  unsigned short* woff_lo = (unsigned short*)w; w += (size_t)384 * 256 * 2;
  float* offb = (float*)w;  w += (size_t)4096 * 384 * 4;
  float* qb   = (float*)w;  w += (size_t)4096 * 256 * 4;
  unsigned short* wtd_bf = (unsigned short*)w; w += (size_t)4096 * 256 * 2;

  // 1) small conversions (736 blocks)
  cvt_all<<<F5 / 256, 256, 0, stream>>>(
      in_feats, W_kv, W_q, W_out, W_off,
      if_hi, if_lo, wkv_bf, wq_bf, wout_bf, woff_hi, woff_lo);

  // 2) off + q + kv (kv: W-in-LDS once, A f32->reg streamed, no K-loop barriers)
  ubergemm<<<1536, 256, 0, stream>>>(
      sfeats, wkv_bf, if_hi, if_lo, woff_hi, woff_lo, wq_bf,
      b_kv, b_off, b_q, kvt, offb, qb);

  // 3) fused prep + sampling + attention (XCD-partitioned slices)
  sample_attn4<<<(B_ * N_ * HH) / 4, 256, 0, stream>>>(
      kvt, offb, qb, priors, shapes, starts, pencs, wtd_bf);

  // 4) out = weighted @ W_out^T + b_out
  gemm_out<<<dim3(2, 32), 256, 0, stream>>>(wtd_bf, wout_bf, b_out, out);
}

// Round 11
// 87.093 us; speedup vs baseline: 1.1750x; 1.1750x over previous
//
#include <hip/hip_runtime.h>
#include <cstddef>

#define B_  2
#define N_  2048
#define L_  5
#define HH  8
#define P_  4
#define S_  21824
#define DQK 32

using bf16x8 = __attribute__((ext_vector_type(8))) short;
using f32x4  = __attribute__((ext_vector_type(4))) float;
using us8    = __attribute__((ext_vector_type(8))) unsigned short;

__device__ __forceinline__ unsigned short f2b(float f) {
  unsigned u = __builtin_bit_cast(unsigned, f);
  u += 0x7FFFu + ((u >> 16) & 1u);            // round-to-nearest-even
  return (unsigned short)(u >> 16);
}
__device__ __forceinline__ float b2f(unsigned short h) {
  return __builtin_bit_cast(float, ((unsigned)h) << 16);
}
// packed f32x2 -> bf16x2 (RNE): lo -> low16, hi -> high16
__device__ __forceinline__ unsigned cvtpk(float lo, float hi) {
  unsigned r;
  asm("v_cvt_pk_bf16_f32 %0, %1, %2" : "=v"(r) : "v"(lo), "v"(hi));
  return r;
}

__device__ __forceinline__ void gld_lds16(const void* g, void* l) {
  __builtin_amdgcn_global_load_lds(
      (const __attribute__((address_space(1))) unsigned int*)g,
      (__attribute__((address_space(3))) unsigned int*)l, 16, 0, 0);
}

// DPP-based add: v += permuted(v). VALU pipe, no LDS round-trip.
template <int CTRL>
__device__ __forceinline__ float dppadd(float v) {
  const int x = __builtin_bit_cast(int, v);
  return v + __builtin_bit_cast(float,
      __builtin_amdgcn_update_dpp(x, x, CTRL, 0xF, 0xF, false));
}

// ---------------------------------------------------------------------------
// cvt_all (R7 form): sfeats + in_feats(hi/lo) + weights.
// ---------------------------------------------------------------------------
#define E0 1396736   // sfeats -> sf_bf           (43648*256/8)
#define E1 1527808   // + in_feats -> if_hi        (4096*256/8)
#define E2 1658880   // + in_feats -> if_lo        (4096*256/8)
#define E3 1675264   // + W_kv -> wkv_bf           (512*256/8)
#define E4 1683456   // + W_q  -> wq_bf            (256*256/8)
#define E5 1691648   // + W_out -> wout_bf         (256*256/8)
#define E6 1703936   // + W_off(pad384) -> woff_hi (384*256/8)
#define E7 1716224   // + W_off(pad384) -> woff_lo (384*256/8)

__device__ __forceinline__ void cvt8_plain(const float* s, unsigned short* d, int u) {
  const float4 a = ((const float4*)s)[2 * u];
  const float4 b = ((const float4*)s)[2 * u + 1];
  us8 o;
  o[0] = f2b(a.x); o[1] = f2b(a.y); o[2] = f2b(a.z); o[3] = f2b(a.w);
  o[4] = f2b(b.x); o[5] = f2b(b.y); o[6] = f2b(b.z); o[7] = f2b(b.w);
  ((us8*)d)[u] = o;
}
__device__ __forceinline__ unsigned short f2b_lo(float x) {
  return f2b(x - b2f(f2b(x)));
}
__device__ __forceinline__ void cvt8_lo(const float* s, unsigned short* d, int u) {
  const float4 a = ((const float4*)s)[2 * u];
  const float4 b = ((const float4*)s)[2 * u + 1];
  us8 o;
  o[0] = f2b_lo(a.x); o[1] = f2b_lo(a.y); o[2] = f2b_lo(a.z); o[3] = f2b_lo(a.w);
  o[4] = f2b_lo(b.x); o[5] = f2b_lo(b.y); o[6] = f2b_lo(b.z); o[7] = f2b_lo(b.w);
  ((us8*)d)[u] = o;
}

__global__ __launch_bounds__(256) void cvt_all(
    const float* __restrict__ sfeats, const float* __restrict__ in_feats,
    const float* __restrict__ W_kv, const float* __restrict__ W_q,
    const float* __restrict__ W_out, const float* __restrict__ W_off,
    unsigned short* __restrict__ sf_bf, unsigned short* __restrict__ if_hi,
    unsigned short* __restrict__ if_lo, unsigned short* __restrict__ wkv_bf,
    unsigned short* __restrict__ wq_bf, unsigned short* __restrict__ wout_bf,
    unsigned short* __restrict__ woff_hi, unsigned short* __restrict__ woff_lo) {
  const int i = blockIdx.x * 256 + threadIdx.x;
  if      (i < E0) cvt8_plain(sfeats, sf_bf, i);
  else if (i < E1) cvt8_plain(in_feats, if_hi, i - E0);
  else if (i < E2) cvt8_lo(in_feats, if_lo, i - E1);
  else if (i < E3) cvt8_plain(W_kv, wkv_bf, i - E2);
  else if (i < E4) cvt8_plain(W_q, wq_bf, i - E3);
  else if (i < E5) cvt8_plain(W_out, wout_bf, i - E4);
  else if (i < E6) {
    const int u = i - E5;
    if ((u >> 5) < 320) cvt8_plain(W_off, woff_hi, u);
    else ((us8*)woff_hi)[u] = (us8)0;
  } else {
    const int u = i - E6;
    if ((u >> 5) < 320) cvt8_lo(W_off, woff_lo, u);
    else ((us8*)woff_lo)[u] = (us8)0;
  }
}

// ---------------------------------------------------------------------------
// Classic staged MFMA tile (128x128, BK=64) for off/q/out (proven R7 body).
// ---------------------------------------------------------------------------
__device__ __forceinline__ void mfma_compute(
    const unsigned short* As, const unsigned short* Bs,
    int wr, int wc, int fr, int fq, f32x4 (&acc)[4][4]) {
#pragma unroll
  for (int kk = 0; kk < 2; ++kk) {
    bf16x8 af[4], bfv[4];
#pragma unroll
    for (int i = 0; i < 4; ++i) {
      const int ar = wr * 64 + i * 16 + fr;
      const int cha = (kk * 4 + fq) ^ (ar & 7);
      af[i] = *(const bf16x8*)(As + ar * 64 + cha * 8);
      const int br = wc * 64 + i * 16 + fr;
      const int chb = (kk * 4 + fq) ^ (br & 7);
      bfv[i] = *(const bf16x8*)(Bs + br * 64 + chb * 8);
    }
#pragma unroll
    for (int i = 0; i < 4; ++i)
#pragma unroll
      for (int j = 0; j < 4; ++j)
        acc[i][j] = __builtin_amdgcn_mfma_f32_16x16x32_bf16(
            af[i], bfv[j], acc[i][j], 0, 0, 0);
  }
}

__device__ __forceinline__ void mfma_tile_bf16(
    const unsigned short* __restrict__ Ap, const unsigned short* __restrict__ Wp,
    unsigned short* As, unsigned short* Bs,
    int row0, int col0, int wv, int wr, int wc, int fr, int fq,
    int srow, int sch, f32x4 (&acc)[4][4]) {
  for (int k0 = 0; k0 < 256; k0 += 64) {
#pragma unroll
    for (int i = 0; i < 4; ++i) {
      const int r = i * 32 + srow;
      const int ca = sch ^ (r & 7);
      gld_lds16(Ap + (size_t)(row0 + r) * 256 + k0 + ca * 8,
                As + (size_t)(i * 32 + wv * 8) * 64);
      gld_lds16(Wp + (size_t)(col0 + r) * 256 + k0 + ca * 8,
                Bs + (size_t)(i * 32 + wv * 8) * 64);
    }
    __syncthreads();
    mfma_compute(As, Bs, wr, wc, fr, fq, acc);
    __syncthreads();
  }
}

// ---------------------------------------------------------------------------
// Ubergemm: off [0,96) | q [96,160) | kv [160,1536).
// kv path: BK=32 double-buffered, counted vmcnt(4) (never 0 mid-loop), raw
// s_barrier; swapped-operand MFMA -> C^T fragments -> dword stores (channels
// contiguous per lane). XCD-grouped kv blocks (4 col-blocks of a row-panel on
// one XCD).
// ---------------------------------------------------------------------------
__global__ __launch_bounds__(256) void ubergemm(
    const unsigned short* __restrict__ sf_bf,
    const unsigned short* __restrict__ wkv_bf,
    const unsigned short* __restrict__ if_hi,
    const unsigned short* __restrict__ if_lo,
    const unsigned short* __restrict__ woff_hi,
    const unsigned short* __restrict__ woff_lo,
    const unsigned short* __restrict__ wq_bf,
    const float* __restrict__ b_kv, const float* __restrict__ b_off,
    const float* __restrict__ b_q,
    unsigned short* __restrict__ kvt, float* __restrict__ offb,
    float* __restrict__ qb) {
  __shared__ __align__(16) unsigned short lds[128 * 128];   // 32 KB

  const int tid = threadIdx.x;
  const int lane = tid & 63;
  const int wv = tid >> 6;
  const int wr = wv >> 1, wc = wv & 1;
  const int fr = lane & 15, fq = lane >> 4;
  const int bx = blockIdx.x;

  f32x4 acc[4][4] = {};

  if (bx >= 160) {          // ---- kv path ----
    const int t = bx - 160;
    const int x = t & 7;            // XCD slot
    const int idx = t >> 3;
    const int c = idx & 3;          // column block 0..3
    const int g = (idx >> 2) * 8 + x;  // row panel
    if (g >= 341) return;
    const int row0 = g * 128;
    const int col0 = c * 128;

    // double buffers: A[2][128][32], B[2][128][32] bf16 (8KB each)
    unsigned short* Ab[2] = {lds, lds + 4096};
    unsigned short* Bb[2] = {lds + 8192, lds + 12288};

    // stage macro: 2 A-chunks + 2 B-chunks per thread (4 vmem ops)
#define KV_STAGE(KK, BUF)                                                     \
    {                                                                         \
      _Pragma("unroll")                                                       \
      for (int ld = 0; ld < 2; ++ld) {                                        \
        const int ci = ld * 256 + tid;                                        \
        const int rw = ci >> 2, cc = ci & 3;                                  \
        const int ca = cc ^ (rw & 3);                                         \
        gld_lds16(sf_bf + (size_t)(row0 + rw) * 256 + (KK) * 32 + ca * 8,     \
                  Ab[BUF] + (size_t)(ld * 256 + wv * 64) * 8);                \
        gld_lds16(wkv_bf + (size_t)(col0 + rw) * 256 + (KK) * 32 + ca * 8,    \
                  Bb[BUF] + (size_t)(ld * 256 + wv * 64) * 8);                \
      }                                                                       \
    }

    KV_STAGE(0, 0);
#pragma unroll
    for (int k = 0; k < 8; ++k) {
      if (k < 7) {
        KV_STAGE(k + 1, (k + 1) & 1);
        asm volatile("s_waitcnt vmcnt(4)" ::: "memory");
      } else {
        asm volatile("s_waitcnt vmcnt(0)" ::: "memory");
      }
      __builtin_amdgcn_s_barrier();
      __builtin_amdgcn_sched_barrier(0);
      const unsigned short* Ac = Ab[k & 1];
      const unsigned short* Bc = Bb[k & 1];
      bf16x8 af[4], bfv[4];
#pragma unroll
      for (int i = 0; i < 4; ++i) {
        const int ar = wr * 64 + i * 16 + fr;
        af[i] = *(const bf16x8*)(Ac + (ar * 4 + (fq ^ (ar & 3))) * 8);
      }
#pragma unroll
      for (int j = 0; j < 4; ++j) {
        const int nr = wc * 64 + j * 16 + fr;
        bfv[j] = *(const bf16x8*)(Bc + (nr * 4 + (fq ^ (nr & 3))) * 8);
      }
#pragma unroll
      for (int j = 0; j < 4; ++j)
#pragma unroll
        for (int i = 0; i < 4; ++i)
          acc[j][i] = __builtin_amdgcn_mfma_f32_16x16x32_bf16(
              bfv[j], af[i], acc[j][i], 0, 0, 0);   // swapped: C^T fragments
      __builtin_amdgcn_s_barrier();
    }
#undef KV_STAGE

    // epilogue: lane holds 4 consecutive channels per tile -> dword stores
#pragma unroll
    for (int j = 0; j < 4; ++j) {
      const int c0 = col0 + wc * 64 + j * 16 + fq * 4;
      const float4 bb = *(const float4*)(b_kv + c0);
      const int h = c0 >> 6;
      const int cc = c0 & 63;
#pragma unroll
      for (int i = 0; i < 4; ++i) {
        const int sl = row0 + wr * 64 + i * 16 + fr;
        const int b = (sl >= S_) ? 1 : 0;
        const int s = sl - b * S_;
        unsigned* dst = (unsigned*)(kvt + ((size_t)(b * HH + h) * S_ + s) * 64 + cc);
        dst[0] = cvtpk(acc[j][i][0] + bb.x, acc[j][i][1] + bb.y);
        dst[1] = cvtpk(acc[j][i][2] + bb.z, acc[j][i][3] + bb.w);
      }
    }
    return;
  }

  // ---- off / q paths (classic staged tiles) ----
  unsigned short* As = lds;
  unsigned short* Bs = lds + 128 * 64;
  const int srow = tid >> 3;
  const int sch = tid & 7;
  int row0, col0, ldc, nbias;
  const float* bias;
  float* Cf;
  if (bx < 96) {            // off: 3 K-segments, bf16x3
    col0 = (bx % 3) * 128; row0 = (bx / 3) * 128;
    bias = b_off; Cf = offb; ldc = 384; nbias = 320;
    mfma_tile_bf16(if_hi, woff_hi, As, Bs, row0, col0, wv, wr, wc, fr, fq, srow, sch, acc);
    mfma_tile_bf16(if_hi, woff_lo, As, Bs, row0, col0, wv, wr, wc, fr, fq, srow, sch, acc);
    mfma_tile_bf16(if_lo, woff_hi, As, Bs, row0, col0, wv, wr, wc, fr, fq, srow, sch, acc);
  } else {                  // q
    const int t = bx - 96;
    col0 = (t & 1) * 128; row0 = (t >> 1) * 128;
    bias = b_q; Cf = qb; ldc = 256; nbias = 256;
    mfma_tile_bf16(if_hi, wq_bf, As, Bs, row0, col0, wv, wr, wc, fr, fq, srow, sch, acc);
  }

#pragma unroll
  for (int j = 0; j < 4; ++j) {
    const int n = col0 + wc * 64 + j * 16 + fr;
    const float bv = (n < nbias) ? bias[n] : 0.f;
#pragma unroll
    for (int i = 0; i < 4; ++i) {
      const int mbase = row0 + wr * 64 + i * 16 + fq * 4;
#pragma unroll
      for (int r = 0; r < 4; ++r)
        Cf[(size_t)(mbase + r) * ldc + n] = acc[i][j][r] + bv;
    }
  }
}

// ---------------------------------------------------------------------------
// out-projection GEMM: bf16 MFMA, f32 out.
// ---------------------------------------------------------------------------
__global__ __launch_bounds__(256) void gemm_out(
    const unsigned short* __restrict__ A, const unsigned short* __restrict__ Wt,
    const float* __restrict__ bias, float* __restrict__ C) {
  __shared__ __align__(16) unsigned short As[128 * 64];
  __shared__ __align__(16) unsigned short Bs[128 * 64];
  const int tid = threadIdx.x;
  const int lane = tid & 63;
  const int wv = tid >> 6;
  const int wr = wv >> 1, wc = wv & 1;
  const int fr = lane & 15, fq = lane >> 4;
  const int row0 = blockIdx.y * 128, col0 = blockIdx.x * 128;
  const int srow = tid >> 3, sch = tid & 7;
  f32x4 acc[4][4] = {};
  mfma_tile_bf16(A, Wt, As, Bs, row0, col0, wv, wr, wc, fr, fq, srow, sch, acc);
#pragma unroll
  for (int j = 0; j < 4; ++j) {
    const int n = col0 + wc * 64 + j * 16 + fr;
    const float bv = bias[n];
#pragma unroll
    for (int i = 0; i < 4; ++i) {
      const int mbase = row0 + wr * 64 + i * 16 + fq * 4;
#pragma unroll
      for (int r = 0; r < 4; ++r)
        C[(size_t)(mbase + r) * 256 + n] = acc[i][j][r] + bv;
    }
  }
}

// ---------------------------------------------------------------------------
// sample_attn4: XCD-partitioned slices; DPP reduce; 1-deep gather prefetch.
// ---------------------------------------------------------------------------
__global__ __launch_bounds__(256) void sample_attn4(
    const unsigned short* __restrict__ kvt, // [B*HH, S, 64] bf16
    const float* __restrict__ offb,         // [B*N, 384]
    const float* __restrict__ qb,           // [B*N, 256]
    const float* __restrict__ priors,       // [B, N, L, 2]
    const int* __restrict__ shapes,         // [L, 2] (H, W)
    const int* __restrict__ starts,         // [L]
    const float* __restrict__ pencs,        // [HH, 20, 32]
    unsigned short* __restrict__ wtd) {     // [B*N, 256] bf16
  __shared__ __align__(16) int pbuf[4][20][8];
  const int wv = threadIdx.x >> 6;
  const int lane = threadIdx.x & 63;
  const int beta = blockIdx.x;
  const int sig = (beta & 7) * 2 + ((beta >> 3) & 1);  // slice 0..15
  const int chunk = beta >> 4;                          // 0..511
  const int h = sig & 7;
  const int b = sig >> 3;
  const int bn = b * N_ + chunk * 4 + wv;
  const int j = lane & 31;
  const int half = lane >> 5;

  if (lane < 20) {
    const int pp = lane;
    const int l = pp >> 2;
    const float2 oxy = *(const float2*)(offb + (size_t)bn * 384 + h * 40 + pp * 2);
    const float2 pxy = *(const float2*)(priors + ((size_t)bn * 5 + l) * 2);
    const int Wd = shapes[l * 2 + 1];
    const int Hd = shapes[l * 2 + 0];
    const int st = starts[l];
    const float Wf = (float)Wd, Hf = (float)Hd;
    const float x = (pxy.x + oxy.x / Wf) * Wf - 0.5f;
    const float y = (pxy.y + oxy.y / Hf) * Hf - 0.5f;
    const float x0f = floorf(x), y0f = floorf(y);
    const float fx = x - x0f, fy = y - y0f;
    const int xi = (int)x0f, yi = (int)y0f;
    int a[4]; float w[4];
#pragma unroll
    for (int dy = 0; dy < 2; ++dy)
#pragma unroll
      for (int dx = 0; dx < 2; ++dx) {
        const int xc = xi + dx, yc = yi + dy;
        const bool valid = (xc >= 0) & (xc < Wd) & (yc >= 0) & (yc < Hd);
        const float wt = (dx ? fx : 1.f - fx) * (dy ? fy : 1.f - fy);
        const int xcc = min(max(xc, 0), Wd - 1);
        const int ycc = min(max(yc, 0), Hd - 1);
        a[dy * 2 + dx] = (st + ycc * Wd + xcc) * 32;
        w[dy * 2 + dx] = valid ? wt : 0.f;
      }
    *(int4*)&pbuf[wv][pp][0] = make_int4(a[0], a[1], a[2], a[3]);
    *(float4*)&pbuf[wv][pp][4] = make_float4(w[0], w[1], w[2], w[3]);
  }

  const int jc = j & 15;
  float2 q2 = *(const float2*)(qb + (size_t)bn * 256 + h * DQK + 2 * jc);
  q2.x *= 0.17677669529663687f;
  q2.y *= 0.17677669529663687f;
  float qpe[10];
#pragma unroll
  for (int i = 0; i < 10; ++i) {
    const float2 pe = *(const float2*)(
        pencs + ((size_t)h * 20 + 2 * i + half) * DQK + 2 * jc);
    qpe[i] = q2.x * pe.x + q2.y * pe.y;
  }

  const unsigned* kvd = (const unsigned*)(kvt + (size_t)(b * HH + h) * (S_ * 64));
  int4 aa[2]; float4 ww[2]; unsigned g[2][4];
  aa[0] = *(const int4*)&pbuf[wv][half][0];
  ww[0] = *(const float4*)&pbuf[wv][half][4];
  g[0][0] = kvd[(unsigned)aa[0].x + j];
  g[0][1] = kvd[(unsigned)aa[0].y + j];
  g[0][2] = kvd[(unsigned)aa[0].z + j];
  g[0][3] = kvd[(unsigned)aa[0].w + j];

  float2 sam[10];
  float lg[10];
#pragma unroll
  for (int i = 0; i < 10; ++i) {
    const int cur = i & 1, nxt = cur ^ 1;
    if (i < 9) {
      aa[nxt] = *(const int4*)&pbuf[wv][2 * (i + 1) + half][0];
      ww[nxt] = *(const float4*)&pbuf[wv][2 * (i + 1) + half][4];
      g[nxt][0] = kvd[(unsigned)aa[nxt].x + j];
      g[nxt][1] = kvd[(unsigned)aa[nxt].y + j];
      g[nxt][2] = kvd[(unsigned)aa[nxt].z + j];
      g[nxt][3] = kvd[(unsigned)aa[nxt].w + j];
    }
    const float4 wt = ww[cur];
    const unsigned g0 = g[cur][0], g1 = g[cur][1], g2 = g[cur][2], g3 = g[cur][3];
    const float lo0 = __builtin_bit_cast(float, g0 << 16);
    const float hi0 = __builtin_bit_cast(float, g0 & 0xFFFF0000u);
    const float lo1 = __builtin_bit_cast(float, g1 << 16);
    const float hi1 = __builtin_bit_cast(float, g1 & 0xFFFF0000u);
    const float lo2 = __builtin_bit_cast(float, g2 << 16);
    const float hi2 = __builtin_bit_cast(float, g2 & 0xFFFF0000u);
    const float lo3 = __builtin_bit_cast(float, g3 << 16);
    const float hi3 = __builtin_bit_cast(float, g3 & 0xFFFF0000u);
    float vx = wt.x * lo0;  vx = fmaf(wt.y, lo1, vx);
    vx = fmaf(wt.z, lo2, vx); vx = fmaf(wt.w, lo3, vx);
    float vy = wt.x * hi0;  vy = fmaf(wt.y, hi1, vy);
    vy = fmaf(wt.z, hi2, vy); vy = fmaf(wt.w, hi3, vy);
    sam[i].x = vx; sam[i].y = vy;
    float part = (j < 16) ? fmaf(q2.x, vx, fmaf(q2.y, vy, qpe[i])) : 0.f;
    part = dppadd<0xB1>(part);    // quad_perm xor1
    part = dppadd<0x4E>(part);    // quad_perm xor2
    part = dppadd<0x124>(part);   // row_ror:4
    part = dppadd<0x128>(part);   // row_ror:8 -> row16 sum
    lg[i] = part + __shfl_xor(part, 16, 64);
  }

  float mx = lg[0];
#pragma unroll
  for (int i = 1; i < 10; ++i) mx = fmaxf(mx, lg[i]);
  mx = fmaxf(mx, __shfl_xor(mx, 32, 64));
  float se = 0.f;
#pragma unroll
  for (int i = 0; i < 10; ++i) {
    lg[i] = __expf(lg[i] - mx);
    se += lg[i];
  }
  se += __shfl_xor(se, 32, 64);
  const float inv = 1.f / se;

  float ax = 0.f, ay = 0.f;
#pragma unroll
  for (int i = 0; i < 10; ++i) {
    ax = fmaf(lg[i], sam[i].x, ax);
    ay = fmaf(lg[i], sam[i].y, ay);
  }
  ax += __shfl_xor(ax, 32, 64);
  ay += __shfl_xor(ay, 32, 64);

  if (half == 0 && j >= 16) {
    const unsigned u = (unsigned)f2b(ax * inv) | ((unsigned)f2b(ay * inv) << 16);
    ((unsigned*)wtd)[(size_t)bn * 128 + h * 16 + (j - 16)] = u;
  }
}

// ---------------------------------------------------------------------------
extern "C" void kernel_launch(void* const* d_in, const int* in_sizes, int n_in,
                              void* d_out, int out_size, void* d_ws, size_t ws_size,
                              hipStream_t stream) {
  const float* in_feats = (const float*)d_in[0];
  const float* priors   = (const float*)d_in[1];
  const float* sfeats   = (const float*)d_in[2];
  const int*   shapes   = (const int*)d_in[3];
  const int*   starts   = (const int*)d_in[4];
  const float* W_off    = (const float*)d_in[5];
  const float* b_off    = (const float*)d_in[6];
  const float* W_q      = (const float*)d_in[7];
  const float* b_q      = (const float*)d_in[8];
  const float* W_kv     = (const float*)d_in[9];
  const float* b_kv     = (const float*)d_in[10];
  const float* pencs    = (const float*)d_in[11];
  const float* W_out    = (const float*)d_in[12];
  const float* b_out    = (const float*)d_in[13];
  float* out = (float*)d_out;

  char* w = (char*)d_ws;
  unsigned short* kvt = (unsigned short*)w;            // 44.7 MB
  w += (size_t)B_ * HH * S_ * 64 * 2;
  unsigned short* sf_bf = (unsigned short*)w;          // 22.3 MB
  w += (size_t)B_ * S_ * 256 * 2;
  unsigned short* if_hi = (unsigned short*)w; w += (size_t)4096 * 256 * 2;
  unsigned short* if_lo = (unsigned short*)w; w += (size_t)4096 * 256 * 2;
  unsigned short* wkv_bf = (unsigned short*)w;  w += (size_t)512 * 256 * 2;
  unsigned short* wq_bf  = (unsigned short*)w;  w += (size_t)256 * 256 * 2;
  unsigned short* wout_bf = (unsigned short*)w; w += (size_t)256 * 256 * 2;
  unsigned short* woff_hi = (unsigned short*)w; w += (size_t)384 * 256 * 2;
  unsigned short* woff_lo = (unsigned short*)w; w += (size_t)384 * 256 * 2;
  float* offb = (float*)w;  w += (size_t)4096 * 384 * 4;
  float* qb   = (float*)w;  w += (size_t)4096 * 256 * 4;
  unsigned short* wtd_bf = (unsigned short*)w; w += (size_t)4096 * 256 * 2;

  // 1) conversions (6704 blocks)
  cvt_all<<<E7 / 256, 256, 0, stream>>>(
      sfeats, in_feats, W_kv, W_q, W_out, W_off,
      sf_bf, if_hi, if_lo, wkv_bf, wq_bf, wout_bf, woff_hi, woff_lo);

  // 2) off + q + kv (kv: BK=32 dbuf, counted vmcnt, swapped-store epilogue)
  ubergemm<<<1536, 256, 0, stream>>>(
      sf_bf, wkv_bf, if_hi, if_lo, woff_hi, woff_lo, wq_bf,
      b_kv, b_off, b_q, kvt, offb, qb);

  // 3) fused prep + sampling + attention (XCD-partitioned slices)
  sample_attn4<<<(B_ * N_ * HH) / 4, 256, 0, stream>>>(
      kvt, offb, qb, priors, shapes, starts, pencs, wtd_bf);

  // 4) out = weighted @ W_out^T + b_out
  gemm_out<<<dim3(2, 32), 256, 0, stream>>>(wtd_bf, wout_bf, b_out, out);
}

// Round 12
// 86.949 us; speedup vs baseline: 1.1769x; 1.0017x over previous
//
#include <hip/hip_runtime.h>
#include <cstddef>

#define B_  2
#define N_  2048
#define L_  5
#define HH  8
#define P_  4
#define S_  21824
#define DQK 32

using bf16x8 = __attribute__((ext_vector_type(8))) short;
using f32x4  = __attribute__((ext_vector_type(4))) float;
using us8    = __attribute__((ext_vector_type(8))) unsigned short;

__device__ __forceinline__ unsigned short f2b(float f) {
  unsigned u = __builtin_bit_cast(unsigned, f);
  u += 0x7FFFu + ((u >> 16) & 1u);            // round-to-nearest-even
  return (unsigned short)(u >> 16);
}
__device__ __forceinline__ float b2f(unsigned short h) {
  return __builtin_bit_cast(float, ((unsigned)h) << 16);
}
// packed f32x2 -> bf16x2 (RNE): lo -> low16, hi -> high16
__device__ __forceinline__ unsigned cvtpk(float lo, float hi) {
  unsigned r;
  asm("v_cvt_pk_bf16_f32 %0, %1, %2" : "=v"(r) : "v"(lo), "v"(hi));
  return r;
}

__device__ __forceinline__ void gld_lds16(const void* g, void* l) {
  __builtin_amdgcn_global_load_lds(
      (const __attribute__((address_space(1))) unsigned int*)g,
      (__attribute__((address_space(3))) unsigned int*)l, 16, 0, 0);
}

// DPP-based add: v += permuted(v). VALU pipe, no LDS round-trip.
template <int CTRL>
__device__ __forceinline__ float dppadd(float v) {
  const int x = __builtin_bit_cast(int, v);
  return v + __builtin_bit_cast(float,
      __builtin_amdgcn_update_dpp(x, x, CTRL, 0xF, 0xF, false));
}

// ---------------------------------------------------------------------------
// cvt_all: sfeats + in_feats(hi/lo) + weights.
// ---------------------------------------------------------------------------
#define E0 1396736   // sfeats -> sf_bf           (43648*256/8)
#define E1 1527808   // + in_feats -> if_hi        (4096*256/8)
#define E2 1658880   // + in_feats -> if_lo        (4096*256/8)
#define E3 1675264   // + W_kv -> wkv_bf           (512*256/8)
#define E4 1683456   // + W_q  -> wq_bf            (256*256/8)
#define E5 1691648   // + W_out -> wout_bf         (256*256/8)
#define E6 1703936   // + W_off(pad384) -> woff_hi (384*256/8)
#define E7 1716224   // + W_off(pad384) -> woff_lo (384*256/8)

__device__ __forceinline__ void cvt8_plain(const float* s, unsigned short* d, int u) {
  const float4 a = ((const float4*)s)[2 * u];
  const float4 b = ((const float4*)s)[2 * u + 1];
  us8 o;
  o[0] = f2b(a.x); o[1] = f2b(a.y); o[2] = f2b(a.z); o[3] = f2b(a.w);
  o[4] = f2b(b.x); o[5] = f2b(b.y); o[6] = f2b(b.z); o[7] = f2b(b.w);
  ((us8*)d)[u] = o;
}
__device__ __forceinline__ unsigned short f2b_lo(float x) {
  return f2b(x - b2f(f2b(x)));
}
__device__ __forceinline__ void cvt8_lo(const float* s, unsigned short* d, int u) {
  const float4 a = ((const float4*)s)[2 * u];
  const float4 b = ((const float4*)s)[2 * u + 1];
  us8 o;
  o[0] = f2b_lo(a.x); o[1] = f2b_lo(a.y); o[2] = f2b_lo(a.z); o[3] = f2b_lo(a.w);
  o[4] = f2b_lo(b.x); o[5] = f2b_lo(b.y); o[6] = f2b_lo(b.z); o[7] = f2b_lo(b.w);
  ((us8*)d)[u] = o;
}

__global__ __launch_bounds__(256) void cvt_all(
    const float* __restrict__ sfeats, const float* __restrict__ in_feats,
    const float* __restrict__ W_kv, const float* __restrict__ W_q,
    const float* __restrict__ W_out, const float* __restrict__ W_off,
    unsigned short* __restrict__ sf_bf, unsigned short* __restrict__ if_hi,
    unsigned short* __restrict__ if_lo, unsigned short* __restrict__ wkv_bf,
    unsigned short* __restrict__ wq_bf, unsigned short* __restrict__ wout_bf,
    unsigned short* __restrict__ woff_hi, unsigned short* __restrict__ woff_lo) {
  const int i = blockIdx.x * 256 + threadIdx.x;
  if      (i < E0) cvt8_plain(sfeats, sf_bf, i);
  else if (i < E1) cvt8_plain(in_feats, if_hi, i - E0);
  else if (i < E2) cvt8_lo(in_feats, if_lo, i - E1);
  else if (i < E3) cvt8_plain(W_kv, wkv_bf, i - E2);
  else if (i < E4) cvt8_plain(W_q, wq_bf, i - E3);
  else if (i < E5) cvt8_plain(W_out, wout_bf, i - E4);
  else if (i < E6) {
    const int u = i - E5;
    if ((u >> 5) < 320) cvt8_plain(W_off, woff_hi, u);
    else ((us8*)woff_hi)[u] = (us8)0;
  } else {
    const int u = i - E6;
    if ((u >> 5) < 320) cvt8_lo(W_off, woff_lo, u);
    else ((us8*)woff_lo)[u] = (us8)0;
  }
}

// ---------------------------------------------------------------------------
// Classic staged MFMA tile (128x128, BK=64) for off/q/out (proven body).
// ---------------------------------------------------------------------------
__device__ __forceinline__ void mfma_compute(
    const unsigned short* As, const unsigned short* Bs,
    int wr, int wc, int fr, int fq, f32x4 (&acc)[4][4]) {
#pragma unroll
  for (int kk = 0; kk < 2; ++kk) {
    bf16x8 af[4], bfv[4];
#pragma unroll
    for (int i = 0; i < 4; ++i) {
      const int ar = wr * 64 + i * 16 + fr;
      const int cha = (kk * 4 + fq) ^ (ar & 7);
      af[i] = *(const bf16x8*)(As + ar * 64 + cha * 8);
      const int br = wc * 64 + i * 16 + fr;
      const int chb = (kk * 4 + fq) ^ (br & 7);
      bfv[i] = *(const bf16x8*)(Bs + br * 64 + chb * 8);
    }
#pragma unroll
    for (int i = 0; i < 4; ++i)
#pragma unroll
      for (int j = 0; j < 4; ++j)
        acc[i][j] = __builtin_amdgcn_mfma_f32_16x16x32_bf16(
            af[i], bfv[j], acc[i][j], 0, 0, 0);
  }
}

__device__ __forceinline__ void mfma_tile_bf16(
    const unsigned short* __restrict__ Ap, const unsigned short* __restrict__ Wp,
    unsigned short* As, unsigned short* Bs,
    int row0, int col0, int wv, int wr, int wc, int fr, int fq,
    int srow, int sch, f32x4 (&acc)[4][4]) {
  for (int k0 = 0; k0 < 256; k0 += 64) {
#pragma unroll
    for (int i = 0; i < 4; ++i) {
      const int r = i * 32 + srow;
      const int ca = sch ^ (r & 7);
      gld_lds16(Ap + (size_t)(row0 + r) * 256 + k0 + ca * 8,
                As + (size_t)(i * 32 + wv * 8) * 64);
      gld_lds16(Wp + (size_t)(col0 + r) * 256 + k0 + ca * 8,
                Bs + (size_t)(i * 32 + wv * 8) * 64);
    }
    __syncthreads();
    mfma_compute(As, Bs, wr, wc, fr, fq, acc);
    __syncthreads();
  }
}

// ---------------------------------------------------------------------------
// Ubergemm: off [0,96) | q [96,160) | kv [160,1536)  (unchanged from R11).
// ---------------------------------------------------------------------------
__global__ __launch_bounds__(256) void ubergemm(
    const unsigned short* __restrict__ sf_bf,
    const unsigned short* __restrict__ wkv_bf,
    const unsigned short* __restrict__ if_hi,
    const unsigned short* __restrict__ if_lo,
    const unsigned short* __restrict__ woff_hi,
    const unsigned short* __restrict__ woff_lo,
    const unsigned short* __restrict__ wq_bf,
    const float* __restrict__ b_kv, const float* __restrict__ b_off,
    const float* __restrict__ b_q,
    unsigned short* __restrict__ kvt, float* __restrict__ offb,
    float* __restrict__ qb) {
  __shared__ __align__(16) unsigned short lds[128 * 128];   // 32 KB

  const int tid = threadIdx.x;
  const int lane = tid & 63;
  const int wv = tid >> 6;
  const int wr = wv >> 1, wc = wv & 1;
  const int fr = lane & 15, fq = lane >> 4;
  const int bx = blockIdx.x;

  f32x4 acc[4][4] = {};

  if (bx >= 160) {          // ---- kv path ----
    const int t = bx - 160;
    const int x = t & 7;
    const int idx = t >> 3;
    const int c = idx & 3;
    const int g = (idx >> 2) * 8 + x;
    if (g >= 341) return;
    const int row0 = g * 128;
    const int col0 = c * 128;

    unsigned short* Ab[2] = {lds, lds + 4096};
    unsigned short* Bb[2] = {lds + 8192, lds + 12288};

#define KV_STAGE(KK, BUF)                                                     \
    {                                                                         \
      _Pragma("unroll")                                                       \
      for (int ld = 0; ld < 2; ++ld) {                                        \
        const int ci = ld * 256 + tid;                                        \
        const int rw = ci >> 2, cc = ci & 3;                                  \
        const int ca = cc ^ (rw & 3);                                         \
        gld_lds16(sf_bf + (size_t)(row0 + rw) * 256 + (KK) * 32 + ca * 8,     \
                  Ab[BUF] + (size_t)(ld * 256 + wv * 64) * 8);                \
        gld_lds16(wkv_bf + (size_t)(col0 + rw) * 256 + (KK) * 32 + ca * 8,    \
                  Bb[BUF] + (size_t)(ld * 256 + wv * 64) * 8);                \
      }                                                                       \
    }

    KV_STAGE(0, 0);
#pragma unroll
    for (int k = 0; k < 8; ++k) {
      if (k < 7) {
        KV_STAGE(k + 1, (k + 1) & 1);
        asm volatile("s_waitcnt vmcnt(4)" ::: "memory");
      } else {
        asm volatile("s_waitcnt vmcnt(0)" ::: "memory");
      }
      __builtin_amdgcn_s_barrier();
      __builtin_amdgcn_sched_barrier(0);
      const unsigned short* Ac = Ab[k & 1];
      const unsigned short* Bc = Bb[k & 1];
      bf16x8 af[4], bfv[4];
#pragma unroll
      for (int i = 0; i < 4; ++i) {
        const int ar = wr * 64 + i * 16 + fr;
        af[i] = *(const bf16x8*)(Ac + (ar * 4 + (fq ^ (ar & 3))) * 8);
      }
#pragma unroll
      for (int j = 0; j < 4; ++j) {
        const int nr = wc * 64 + j * 16 + fr;
        bfv[j] = *(const bf16x8*)(Bc + (nr * 4 + (fq ^ (nr & 3))) * 8);
      }
#pragma unroll
      for (int j = 0; j < 4; ++j)
#pragma unroll
        for (int i = 0; i < 4; ++i)
          acc[j][i] = __builtin_amdgcn_mfma_f32_16x16x32_bf16(
              bfv[j], af[i], acc[j][i], 0, 0, 0);   // swapped: C^T fragments
      __builtin_amdgcn_s_barrier();
    }
#undef KV_STAGE

#pragma unroll
    for (int j = 0; j < 4; ++j) {
      const int c0 = col0 + wc * 64 + j * 16 + fq * 4;
      const float4 bb = *(const float4*)(b_kv + c0);
      const int h = c0 >> 6;
      const int cc = c0 & 63;
#pragma unroll
      for (int i = 0; i < 4; ++i) {
        const int sl = row0 + wr * 64 + i * 16 + fr;
        const int b = (sl >= S_) ? 1 : 0;
        const int s = sl - b * S_;
        unsigned* dst = (unsigned*)(kvt + ((size_t)(b * HH + h) * S_ + s) * 64 + cc);
        dst[0] = cvtpk(acc[j][i][0] + bb.x, acc[j][i][1] + bb.y);
        dst[1] = cvtpk(acc[j][i][2] + bb.z, acc[j][i][3] + bb.w);
      }
    }
    return;
  }

  // ---- off / q paths ----
  unsigned short* As = lds;
  unsigned short* Bs = lds + 128 * 64;
  const int srow = tid >> 3;
  const int sch = tid & 7;
  int row0, col0, ldc, nbias;
  const float* bias;
  float* Cf;
  if (bx < 96) {            // off: 3 K-segments, bf16x3
    col0 = (bx % 3) * 128; row0 = (bx / 3) * 128;
    bias = b_off; Cf = offb; ldc = 384; nbias = 320;
    mfma_tile_bf16(if_hi, woff_hi, As, Bs, row0, col0, wv, wr, wc, fr, fq, srow, sch, acc);
    mfma_tile_bf16(if_hi, woff_lo, As, Bs, row0, col0, wv, wr, wc, fr, fq, srow, sch, acc);
    mfma_tile_bf16(if_lo, woff_hi, As, Bs, row0, col0, wv, wr, wc, fr, fq, srow, sch, acc);
  } else {                  // q
    const int t = bx - 96;
    col0 = (t & 1) * 128; row0 = (t >> 1) * 128;
    bias = b_q; Cf = qb; ldc = 256; nbias = 256;
    mfma_tile_bf16(if_hi, wq_bf, As, Bs, row0, col0, wv, wr, wc, fr, fq, srow, sch, acc);
  }

#pragma unroll
  for (int j = 0; j < 4; ++j) {
    const int n = col0 + wc * 64 + j * 16 + fr;
    const float bv = (n < nbias) ? bias[n] : 0.f;
#pragma unroll
    for (int i = 0; i < 4; ++i) {
      const int mbase = row0 + wr * 64 + i * 16 + fq * 4;
#pragma unroll
      for (int r = 0; r < 4; ++r)
        Cf[(size_t)(mbase + r) * ldc + n] = acc[i][j][r] + bv;
    }
  }
}

// ---------------------------------------------------------------------------
// out-projection GEMM: bf16 MFMA, f32 out.
// ---------------------------------------------------------------------------
__global__ __launch_bounds__(256) void gemm_out(
    const unsigned short* __restrict__ A, const unsigned short* __restrict__ Wt,
    const float* __restrict__ bias, float* __restrict__ C) {
  __shared__ __align__(16) unsigned short As[128 * 64];
  __shared__ __align__(16) unsigned short Bs[128 * 64];
  const int tid = threadIdx.x;
  const int lane = tid & 63;
  const int wv = tid >> 6;
  const int wr = wv >> 1, wc = wv & 1;
  const int fr = lane & 15, fq = lane >> 4;
  const int row0 = blockIdx.y * 128, col0 = blockIdx.x * 128;
  const int srow = tid >> 3, sch = tid & 7;
  f32x4 acc[4][4] = {};
  mfma_tile_bf16(A, Wt, As, Bs, row0, col0, wv, wr, wc, fr, fq, srow, sch, acc);
#pragma unroll
  for (int j = 0; j < 4; ++j) {
    const int n = col0 + wc * 64 + j * 16 + fr;
    const float bv = bias[n];
#pragma unroll
    for (int i = 0; i < 4; ++i) {
      const int mbase = row0 + wr * 64 + i * 16 + fq * 4;
#pragma unroll
      for (int r = 0; r < 4; ++r)
        C[(size_t)(mbase + r) * 256 + n] = acc[i][j][r] + bv;
    }
  }
}

// ---------------------------------------------------------------------------
// sample_attn5: slice-PHASED XCD decode (one 2.8MB slice per XCD at a time,
// fully L2-resident) + 5-deep statically-indexed gather prefetch (20 loads
// in flight per wave).
// beta bits: [phase:1][chunk:9][xcd:3] -> sig = xcd*2 + phase (bijective).
// ---------------------------------------------------------------------------
__global__ __launch_bounds__(256) void sample_attn5(
    const unsigned short* __restrict__ kvt, // [B*HH, S, 64] bf16
    const float* __restrict__ offb,         // [B*N, 384]
    const float* __restrict__ qb,           // [B*N, 256]
    const float* __restrict__ priors,       // [B, N, L, 2]
    const int* __restrict__ shapes,         // [L, 2] (H, W)
    const int* __restrict__ starts,         // [L]
    const float* __restrict__ pencs,        // [HH, 20, 32]
    unsigned short* __restrict__ wtd) {     // [B*N, 256] bf16
  __shared__ __align__(16) int pbuf[4][20][8];
  const int wv = threadIdx.x >> 6;
  const int lane = threadIdx.x & 63;
  const int beta = blockIdx.x;
  const int sig = (beta & 7) * 2 + (beta >> 12);        // slice 0..15
  const int chunk = (beta >> 3) & 511;                  // 0..511
  const int h = sig & 7;
  const int b = sig >> 3;
  const int bn = b * N_ + chunk * 4 + wv;
  const int j = lane & 31;
  const int half = lane >> 5;

  if (lane < 20) {
    const int pp = lane;
    const int l = pp >> 2;
    const float2 oxy = *(const float2*)(offb + (size_t)bn * 384 + h * 40 + pp * 2);
    const float2 pxy = *(const float2*)(priors + ((size_t)bn * 5 + l) * 2);
    const int Wd = shapes[l * 2 + 1];
    const int Hd = shapes[l * 2 + 0];
    const int st = starts[l];
    const float Wf = (float)Wd, Hf = (float)Hd;
    const float x = (pxy.x + oxy.x / Wf) * Wf - 0.5f;
    const float y = (pxy.y + oxy.y / Hf) * Hf - 0.5f;
    const float x0f = floorf(x), y0f = floorf(y);
    const float fx = x - x0f, fy = y - y0f;
    const int xi = (int)x0f, yi = (int)y0f;
    int a[4]; float w[4];
#pragma unroll
    for (int dy = 0; dy < 2; ++dy)
#pragma unroll
      for (int dx = 0; dx < 2; ++dx) {
        const int xc = xi + dx, yc = yi + dy;
        const bool valid = (xc >= 0) & (xc < Wd) & (yc >= 0) & (yc < Hd);
        const float wt = (dx ? fx : 1.f - fx) * (dy ? fy : 1.f - fy);
        const int xcc = min(max(xc, 0), Wd - 1);
        const int ycc = min(max(yc, 0), Hd - 1);
        a[dy * 2 + dx] = (st + ycc * Wd + xcc) * 32;
        w[dy * 2 + dx] = valid ? wt : 0.f;
      }
    *(int4*)&pbuf[wv][pp][0] = make_int4(a[0], a[1], a[2], a[3]);
    *(float4*)&pbuf[wv][pp][4] = make_float4(w[0], w[1], w[2], w[3]);
  }

  const int jc = j & 15;
  float2 q2 = *(const float2*)(qb + (size_t)bn * 256 + h * DQK + 2 * jc);
  q2.x *= 0.17677669529663687f;
  q2.y *= 0.17677669529663687f;
  float qpe[10];
#pragma unroll
  for (int i = 0; i < 10; ++i) {
    const float2 pe = *(const float2*)(
        pencs + ((size_t)h * 20 + 2 * i + half) * DQK + 2 * jc);
    qpe[i] = q2.x * pe.x + q2.y * pe.y;
  }

  const unsigned* kvd = (const unsigned*)(kvt + (size_t)(b * HH + h) * (S_ * 64));

  // 5-deep rotation, all indices compile-time (full unroll) -> stays in regs
  float4 wwp[5];
  unsigned g[5][4];
#pragma unroll
  for (int i = 0; i < 5; ++i) {
    const int4 aa = *(const int4*)&pbuf[wv][2 * i + half][0];
    wwp[i] = *(const float4*)&pbuf[wv][2 * i + half][4];
    g[i][0] = kvd[(unsigned)aa.x + j];
    g[i][1] = kvd[(unsigned)aa.y + j];
    g[i][2] = kvd[(unsigned)aa.z + j];
    g[i][3] = kvd[(unsigned)aa.w + j];
  }

  float2 sam[10];
  float lg[10];
#pragma unroll
  for (int i = 0; i < 10; ++i) {
    const int s = i % 5;   // constant after unroll
    const float4 wt = wwp[s];
    const unsigned g0 = g[s][0], g1 = g[s][1], g2 = g[s][2], g3 = g[s][3];
    if (i < 5) {           // refill slot s with pair i+5
      const int4 aa = *(const int4*)&pbuf[wv][2 * (i + 5) + half][0];
      wwp[s] = *(const float4*)&pbuf[wv][2 * (i + 5) + half][4];
      g[s][0] = kvd[(unsigned)aa.x + j];
      g[s][1] = kvd[(unsigned)aa.y + j];
      g[s][2] = kvd[(unsigned)aa.z + j];
      g[s][3] = kvd[(unsigned)aa.w + j];
    }
    const float lo0 = __builtin_bit_cast(float, g0 << 16);
    const float hi0 = __builtin_bit_cast(float, g0 & 0xFFFF0000u);
    const float lo1 = __builtin_bit_cast(float, g1 << 16);
    const float hi1 = __builtin_bit_cast(float, g1 & 0xFFFF0000u);
    const float lo2 = __builtin_bit_cast(float, g2 << 16);
    const float hi2 = __builtin_bit_cast(float, g2 & 0xFFFF0000u);
    const float lo3 = __builtin_bit_cast(float, g3 << 16);
    const float hi3 = __builtin_bit_cast(float, g3 & 0xFFFF0000u);
    float vx = wt.x * lo0;  vx = fmaf(wt.y, lo1, vx);
    vx = fmaf(wt.z, lo2, vx); vx = fmaf(wt.w, lo3, vx);
    float vy = wt.x * hi0;  vy = fmaf(wt.y, hi1, vy);
    vy = fmaf(wt.z, hi2, vy); vy = fmaf(wt.w, hi3, vy);
    sam[i].x = vx; sam[i].y = vy;
    float part = (j < 16) ? fmaf(q2.x, vx, fmaf(q2.y, vy, qpe[i])) : 0.f;
    part = dppadd<0xB1>(part);    // quad_perm xor1
    part = dppadd<0x4E>(part);    // quad_perm xor2
    part = dppadd<0x124>(part);   // row_ror:4
    part = dppadd<0x128>(part);   // row_ror:8 -> row16 sum
    lg[i] = part + __shfl_xor(part, 16, 64);
  }

  float mx = lg[0];
#pragma unroll
  for (int i = 1; i < 10; ++i) mx = fmaxf(mx, lg[i]);
  mx = fmaxf(mx, __shfl_xor(mx, 32, 64));
  float se = 0.f;
#pragma unroll
  for (int i = 0; i < 10; ++i) {
    lg[i] = __expf(lg[i] - mx);
    se += lg[i];
  }
  se += __shfl_xor(se, 32, 64);
  const float inv = 1.f / se;

  float ax = 0.f, ay = 0.f;
#pragma unroll
  for (int i = 0; i < 10; ++i) {
    ax = fmaf(lg[i], sam[i].x, ax);
    ay = fmaf(lg[i], sam[i].y, ay);
  }
  ax += __shfl_xor(ax, 32, 64);
  ay += __shfl_xor(ay, 32, 64);

  if (half == 0 && j >= 16) {
    const unsigned u = (unsigned)f2b(ax * inv) | ((unsigned)f2b(ay * inv) << 16);
    ((unsigned*)wtd)[(size_t)bn * 128 + h * 16 + (j - 16)] = u;
  }
}

// ---------------------------------------------------------------------------
extern "C" void kernel_launch(void* const* d_in, const int* in_sizes, int n_in,
                              void* d_out, int out_size, void* d_ws, size_t ws_size,
                              hipStream_t stream) {
  const float* in_feats = (const float*)d_in[0];
  const float* priors   = (const float*)d_in[1];
  const float* sfeats   = (const float*)d_in[2];
  const int*   shapes   = (const int*)d_in[3];
  const int*   starts   = (const int*)d_in[4];
  const float* W_off    = (const float*)d_in[5];
  const float* b_off    = (const float*)d_in[6];
  const float* W_q      = (const float*)d_in[7];
  const float* b_q      = (const float*)d_in[8];
  const float* W_kv     = (const float*)d_in[9];
  const float* b_kv     = (const float*)d_in[10];
  const float* pencs    = (const float*)d_in[11];
  const float* W_out    = (const float*)d_in[12];
  const float* b_out    = (const float*)d_in[13];
  float* out = (float*)d_out;

  char* w = (char*)d_ws;
  unsigned short* kvt = (unsigned short*)w;            // 44.7 MB
  w += (size_t)B_ * HH * S_ * 64 * 2;
  unsigned short* sf_bf = (unsigned short*)w;          // 22.3 MB
  w += (size_t)B_ * S_ * 256 * 2;
  unsigned short* if_hi = (unsigned short*)w; w += (size_t)4096 * 256 * 2;
  unsigned short* if_lo = (unsigned short*)w; w += (size_t)4096 * 256 * 2;
  unsigned short* wkv_bf = (unsigned short*)w;  w += (size_t)512 * 256 * 2;
  unsigned short* wq_bf  = (unsigned short*)w;  w += (size_t)256 * 256 * 2;
  unsigned short* wout_bf = (unsigned short*)w; w += (size_t)256 * 256 * 2;
  unsigned short* woff_hi = (unsigned short*)w; w += (size_t)384 * 256 * 2;
  unsigned short* woff_lo = (unsigned short*)w; w += (size_t)384 * 256 * 2;
  float* offb = (float*)w;  w += (size_t)4096 * 384 * 4;
  float* qb   = (float*)w;  w += (size_t)4096 * 256 * 4;
  unsigned short* wtd_bf = (unsigned short*)w; w += (size_t)4096 * 256 * 2;

  // 1) conversions (6704 blocks)
  cvt_all<<<E7 / 256, 256, 0, stream>>>(
      sfeats, in_feats, W_kv, W_q, W_out, W_off,
      sf_bf, if_hi, if_lo, wkv_bf, wq_bf, wout_bf, woff_hi, woff_lo);

  // 2) off + q + kv (kv: BK=32 dbuf, counted vmcnt, swapped-store epilogue)
  ubergemm<<<1536, 256, 0, stream>>>(
      sf_bf, wkv_bf, if_hi, if_lo, woff_hi, woff_lo, wq_bf,
      b_kv, b_off, b_q, kvt, offb, qb);

  // 3) fused prep + sampling + attention (slice-phased XCD decode)
  sample_attn5<<<(B_ * N_ * HH) / 4, 256, 0, stream>>>(
      kvt, offb, qb, priors, shapes, starts, pencs, wtd_bf);

  // 4) out = weighted @ W_out^T + b_out
  gemm_out<<<dim3(2, 32), 256, 0, stream>>>(wtd_bf, wout_bf, b_out, out);
}

// Round 14
// 83.450 us; speedup vs baseline: 1.2263x; 1.0419x over previous
//
#include <hip/hip_runtime.h>
#include <cstddef>

#define B_  2
#define N_  2048
#define L_  5
#define HH  8
#define P_  4
#define S_  21824
#define DQK 32

using bf16x8 = __attribute__((ext_vector_type(8))) short;
using f32x4  = __attribute__((ext_vector_type(4))) float;
using us8    = __attribute__((ext_vector_type(8))) unsigned short;
using h2     = __attribute__((ext_vector_type(2))) _Float16;

__device__ __forceinline__ unsigned short f2b(float f) {
  unsigned u = __builtin_bit_cast(unsigned, f);
  u += 0x7FFFu + ((u >> 16) & 1u);            // round-to-nearest-even
  return (unsigned short)(u >> 16);
}
__device__ __forceinline__ float b2f(unsigned short h) {
  return __builtin_bit_cast(float, ((unsigned)h) << 16);
}
// packed f32x2 -> bf16x2 (RNE): lo -> low16, hi -> high16
__device__ __forceinline__ unsigned cvtpk(float lo, float hi) {
  unsigned r;
  asm("v_cvt_pk_bf16_f32 %0, %1, %2" : "=v"(r) : "v"(lo), "v"(hi));
  return r;
}
// packed f32x2 -> f16x2 (RTZ) with explicit bit_casts (builtin returns __fp16x2)
__device__ __forceinline__ h2 pkrtz(float a, float b) {
  return __builtin_bit_cast(h2, __builtin_amdgcn_cvt_pkrtz(a, b));
}
__device__ __forceinline__ unsigned pkrtz_u(float a, float b) {
  return __builtin_bit_cast(unsigned, __builtin_amdgcn_cvt_pkrtz(a, b));
}
__device__ __forceinline__ h2 u2h(unsigned u) { return __builtin_bit_cast(h2, u); }

__device__ __forceinline__ void gld_lds16(const void* g, void* l) {
  __builtin_amdgcn_global_load_lds(
      (const __attribute__((address_space(1))) unsigned int*)g,
      (__attribute__((address_space(3))) unsigned int*)l, 16, 0, 0);
}

// DPP-based add: v += permuted(v). VALU pipe, no LDS round-trip.
template <int CTRL>
__device__ __forceinline__ float dppadd(float v) {
  const int x = __builtin_bit_cast(int, v);
  return v + __builtin_bit_cast(float,
      __builtin_amdgcn_update_dpp(x, x, CTRL, 0xF, 0xF, false));
}

// ---------------------------------------------------------------------------
// cvt_all: sfeats + in_feats(hi/lo) + weights.
// ---------------------------------------------------------------------------
#define E0 1396736   // sfeats -> sf_bf           (43648*256/8)
#define E1 1527808   // + in_feats -> if_hi        (4096*256/8)
#define E2 1658880   // + in_feats -> if_lo        (4096*256/8)
#define E3 1675264   // + W_kv -> wkv_bf           (512*256/8)
#define E4 1683456   // + W_q  -> wq_bf            (256*256/8)
#define E5 1691648   // + W_out -> wout_bf         (256*256/8)
#define E6 1703936   // + W_off(pad384) -> woff_hi (384*256/8)
#define E7 1716224   // + W_off(pad384) -> woff_lo (384*256/8)

__device__ __forceinline__ void cvt8_plain(const float* s, unsigned short* d, int u) {
  const float4 a = ((const float4*)s)[2 * u];
  const float4 b = ((const float4*)s)[2 * u + 1];
  us8 o;
  o[0] = f2b(a.x); o[1] = f2b(a.y); o[2] = f2b(a.z); o[3] = f2b(a.w);
  o[4] = f2b(b.x); o[5] = f2b(b.y); o[6] = f2b(b.z); o[7] = f2b(b.w);
  ((us8*)d)[u] = o;
}
__device__ __forceinline__ unsigned short f2b_lo(float x) {
  return f2b(x - b2f(f2b(x)));
}
__device__ __forceinline__ void cvt8_lo(const float* s, unsigned short* d, int u) {
  const float4 a = ((const float4*)s)[2 * u];
  const float4 b = ((const float4*)s)[2 * u + 1];
  us8 o;
  o[0] = f2b_lo(a.x); o[1] = f2b_lo(a.y); o[2] = f2b_lo(a.z); o[3] = f2b_lo(a.w);
  o[4] = f2b_lo(b.x); o[5] = f2b_lo(b.y); o[6] = f2b_lo(b.z); o[7] = f2b_lo(b.w);
  ((us8*)d)[u] = o;
}

__global__ __launch_bounds__(256) void cvt_all(
    const float* __restrict__ sfeats, const float* __restrict__ in_feats,
    const float* __restrict__ W_kv, const float* __restrict__ W_q,
    const float* __restrict__ W_out, const float* __restrict__ W_off,
    unsigned short* __restrict__ sf_bf, unsigned short* __restrict__ if_hi,
    unsigned short* __restrict__ if_lo, unsigned short* __restrict__ wkv_bf,
    unsigned short* __restrict__ wq_bf, unsigned short* __restrict__ wout_bf,
    unsigned short* __restrict__ woff_hi, unsigned short* __restrict__ woff_lo) {
  const int i = blockIdx.x * 256 + threadIdx.x;
  if      (i < E0) cvt8_plain(sfeats, sf_bf, i);
  else if (i < E1) cvt8_plain(in_feats, if_hi, i - E0);
  else if (i < E2) cvt8_lo(in_feats, if_lo, i - E1);
  else if (i < E3) cvt8_plain(W_kv, wkv_bf, i - E2);
  else if (i < E4) cvt8_plain(W_q, wq_bf, i - E3);
  else if (i < E5) cvt8_plain(W_out, wout_bf, i - E4);
  else if (i < E6) {
    const int u = i - E5;
    if ((u >> 5) < 320) cvt8_plain(W_off, woff_hi, u);
    else ((us8*)woff_hi)[u] = (us8)0;
  } else {
    const int u = i - E6;
    if ((u >> 5) < 320) cvt8_lo(W_off, woff_lo, u);
    else ((us8*)woff_lo)[u] = (us8)0;
  }
}

// ---------------------------------------------------------------------------
// Classic staged MFMA tile (128x128, BK=64) for off/q/out (proven body).
// ---------------------------------------------------------------------------
__device__ __forceinline__ void mfma_compute(
    const unsigned short* As, const unsigned short* Bs,
    int wr, int wc, int fr, int fq, f32x4 (&acc)[4][4]) {
#pragma unroll
  for (int kk = 0; kk < 2; ++kk) {
    bf16x8 af[4], bfv[4];
#pragma unroll
    for (int i = 0; i < 4; ++i) {
      const int ar = wr * 64 + i * 16 + fr;
      const int cha = (kk * 4 + fq) ^ (ar & 7);
      af[i] = *(const bf16x8*)(As + ar * 64 + cha * 8);
      const int br = wc * 64 + i * 16 + fr;
      const int chb = (kk * 4 + fq) ^ (br & 7);
      bfv[i] = *(const bf16x8*)(Bs + br * 64 + chb * 8);
    }
#pragma unroll
    for (int i = 0; i < 4; ++i)
#pragma unroll
      for (int j = 0; j < 4; ++j)
        acc[i][j] = __builtin_amdgcn_mfma_f32_16x16x32_bf16(
            af[i], bfv[j], acc[i][j], 0, 0, 0);
  }
}

__device__ __forceinline__ void mfma_tile_bf16(
    const unsigned short* __restrict__ Ap, const unsigned short* __restrict__ Wp,
    unsigned short* As, unsigned short* Bs,
    int row0, int col0, int wv, int wr, int wc, int fr, int fq,
    int srow, int sch, f32x4 (&acc)[4][4]) {
  for (int k0 = 0; k0 < 256; k0 += 64) {
#pragma unroll
    for (int i = 0; i < 4; ++i) {
      const int r = i * 32 + srow;
      const int ca = sch ^ (r & 7);
      gld_lds16(Ap + (size_t)(row0 + r) * 256 + k0 + ca * 8,
                As + (size_t)(i * 32 + wv * 8) * 64);
      gld_lds16(Wp + (size_t)(col0 + r) * 256 + k0 + ca * 8,
                Bs + (size_t)(i * 32 + wv * 8) * 64);
    }
    __syncthreads();
    mfma_compute(As, Bs, wr, wc, fr, fq, acc);
    __syncthreads();
  }
}

// ---------------------------------------------------------------------------
// Ubergemm: off [0,96) | q [96,160) | kv [160,1536).
// kv path unchanged from R11 except: kvt stored as F16 (v_cvt_pkrtz_f16_f32).
// ---------------------------------------------------------------------------
__global__ __launch_bounds__(256) void ubergemm(
    const unsigned short* __restrict__ sf_bf,
    const unsigned short* __restrict__ wkv_bf,
    const unsigned short* __restrict__ if_hi,
    const unsigned short* __restrict__ if_lo,
    const unsigned short* __restrict__ woff_hi,
    const unsigned short* __restrict__ woff_lo,
    const unsigned short* __restrict__ wq_bf,
    const float* __restrict__ b_kv, const float* __restrict__ b_off,
    const float* __restrict__ b_q,
    unsigned short* __restrict__ kvt, float* __restrict__ offb,
    float* __restrict__ qb) {
  __shared__ __align__(16) unsigned short lds[128 * 128];   // 32 KB

  const int tid = threadIdx.x;
  const int lane = tid & 63;
  const int wv = tid >> 6;
  const int wr = wv >> 1, wc = wv & 1;
  const int fr = lane & 15, fq = lane >> 4;
  const int bx = blockIdx.x;

  f32x4 acc[4][4] = {};

  if (bx >= 160) {          // ---- kv path ----
    const int t = bx - 160;
    const int x = t & 7;
    const int idx = t >> 3;
    const int c = idx & 3;
    const int g = (idx >> 2) * 8 + x;
    if (g >= 341) return;
    const int row0 = g * 128;
    const int col0 = c * 128;

    unsigned short* Ab[2] = {lds, lds + 4096};
    unsigned short* Bb[2] = {lds + 8192, lds + 12288};

#define KV_STAGE(KK, BUF)                                                     \
    {                                                                         \
      _Pragma("unroll")                                                       \
      for (int ld = 0; ld < 2; ++ld) {                                        \
        const int ci = ld * 256 + tid;                                        \
        const int rw = ci >> 2, cc = ci & 3;                                  \
        const int ca = cc ^ (rw & 3);                                         \
        gld_lds16(sf_bf + (size_t)(row0 + rw) * 256 + (KK) * 32 + ca * 8,     \
                  Ab[BUF] + (size_t)(ld * 256 + wv * 64) * 8);                \
        gld_lds16(wkv_bf + (size_t)(col0 + rw) * 256 + (KK) * 32 + ca * 8,    \
                  Bb[BUF] + (size_t)(ld * 256 + wv * 64) * 8);                \
      }                                                                       \
    }

    KV_STAGE(0, 0);
#pragma unroll
    for (int k = 0; k < 8; ++k) {
      if (k < 7) {
        KV_STAGE(k + 1, (k + 1) & 1);
        asm volatile("s_waitcnt vmcnt(4)" ::: "memory");
      } else {
        asm volatile("s_waitcnt vmcnt(0)" ::: "memory");
      }
      __builtin_amdgcn_s_barrier();
      __builtin_amdgcn_sched_barrier(0);
      const unsigned short* Ac = Ab[k & 1];
      const unsigned short* Bc = Bb[k & 1];
      bf16x8 af[4], bfv[4];
#pragma unroll
      for (int i = 0; i < 4; ++i) {
        const int ar = wr * 64 + i * 16 + fr;
        af[i] = *(const bf16x8*)(Ac + (ar * 4 + (fq ^ (ar & 3))) * 8);
      }
#pragma unroll
      for (int j = 0; j < 4; ++j) {
        const int nr = wc * 64 + j * 16 + fr;
        bfv[j] = *(const bf16x8*)(Bc + (nr * 4 + (fq ^ (nr & 3))) * 8);
      }
#pragma unroll
      for (int j = 0; j < 4; ++j)
#pragma unroll
        for (int i = 0; i < 4; ++i)
          acc[j][i] = __builtin_amdgcn_mfma_f32_16x16x32_bf16(
              bfv[j], af[i], acc[j][i], 0, 0, 0);   // swapped: C^T fragments
      __builtin_amdgcn_s_barrier();
    }
#undef KV_STAGE

    // epilogue: lane holds 4 consecutive channels per tile -> f16 dword stores
#pragma unroll
    for (int j = 0; j < 4; ++j) {
      const int c0 = col0 + wc * 64 + j * 16 + fq * 4;
      const float4 bb = *(const float4*)(b_kv + c0);
      const int h = c0 >> 6;
      const int cc = c0 & 63;
#pragma unroll
      for (int i = 0; i < 4; ++i) {
        const int sl = row0 + wr * 64 + i * 16 + fr;
        const int b = (sl >= S_) ? 1 : 0;
        const int s = sl - b * S_;
        unsigned* dst = (unsigned*)(kvt + ((size_t)(b * HH + h) * S_ + s) * 64 + cc);
        dst[0] = pkrtz_u(acc[j][i][0] + bb.x, acc[j][i][1] + bb.y);
        dst[1] = pkrtz_u(acc[j][i][2] + bb.z, acc[j][i][3] + bb.w);
      }
    }
    return;
  }

  // ---- off / q paths ----
  unsigned short* As = lds;
  unsigned short* Bs = lds + 128 * 64;
  const int srow = tid >> 3;
  const int sch = tid & 7;
  int row0, col0, ldc, nbias;
  const float* bias;
  float* Cf;
  if (bx < 96) {            // off: 3 K-segments, bf16x3
    col0 = (bx % 3) * 128; row0 = (bx / 3) * 128;
    bias = b_off; Cf = offb; ldc = 384; nbias = 320;
    mfma_tile_bf16(if_hi, woff_hi, As, Bs, row0, col0, wv, wr, wc, fr, fq, srow, sch, acc);
    mfma_tile_bf16(if_hi, woff_lo, As, Bs, row0, col0, wv, wr, wc, fr, fq, srow, sch, acc);
    mfma_tile_bf16(if_lo, woff_hi, As, Bs, row0, col0, wv, wr, wc, fr, fq, srow, sch, acc);
  } else {                  // q
    const int t = bx - 96;
    col0 = (t & 1) * 128; row0 = (t >> 1) * 128;
    bias = b_q; Cf = qb; ldc = 256; nbias = 256;
    mfma_tile_bf16(if_hi, wq_bf, As, Bs, row0, col0, wv, wr, wc, fr, fq, srow, sch, acc);
  }

#pragma unroll
  for (int j = 0; j < 4; ++j) {
    const int n = col0 + wc * 64 + j * 16 + fr;
    const float bv = (n < nbias) ? bias[n] : 0.f;
#pragma unroll
    for (int i = 0; i < 4; ++i) {
      const int mbase = row0 + wr * 64 + i * 16 + fq * 4;
#pragma unroll
      for (int r = 0; r < 4; ++r)
        Cf[(size_t)(mbase + r) * ldc + n] = acc[i][j][r] + bv;
    }
  }
}

// ---------------------------------------------------------------------------
// out-projection GEMM: bf16 MFMA, f32 out.
// ---------------------------------------------------------------------------
__global__ __launch_bounds__(256) void gemm_out(
    const unsigned short* __restrict__ A, const unsigned short* __restrict__ Wt,
    const float* __restrict__ bias, float* __restrict__ C) {
  __shared__ __align__(16) unsigned short As[128 * 64];
  __shared__ __align__(16) unsigned short Bs[128 * 64];
  const int tid = threadIdx.x;
  const int lane = tid & 63;
  const int wv = tid >> 6;
  const int wr = wv >> 1, wc = wv & 1;
  const int fr = lane & 15, fq = lane >> 4;
  const int row0 = blockIdx.y * 128, col0 = blockIdx.x * 128;
  const int srow = tid >> 3, sch = tid & 7;
  f32x4 acc[4][4] = {};
  mfma_tile_bf16(A, Wt, As, Bs, row0, col0, wv, wr, wc, fr, fq, srow, sch, acc);
#pragma unroll
  for (int j = 0; j < 4; ++j) {
    const int n = col0 + wc * 64 + j * 16 + fr;
    const float bv = bias[n];
#pragma unroll
    for (int i = 0; i < 4; ++i) {
      const int mbase = row0 + wr * 64 + i * 16 + fq * 4;
#pragma unroll
      for (int r = 0; r < 4; ++r)
        C[(size_t)(mbase + r) * 256 + n] = acc[i][j][r] + bv;
    }
  }
}

// ---------------------------------------------------------------------------
// sample_attn6: packed-f16 math. kvt is f16; bilinear = v_pk_fma_f16;
// logit = v_dot2_f32_f16; sam stays packed. Slice-phased XCD decode +
// 5-deep gather prefetch.
// ---------------------------------------------------------------------------
__global__ __launch_bounds__(256) void sample_attn6(
    const unsigned short* __restrict__ kvt, // [B*HH, S, 64] f16
    const float* __restrict__ offb,         // [B*N, 384]
    const float* __restrict__ qb,           // [B*N, 256]
    const float* __restrict__ priors,       // [B, N, L, 2]
    const int* __restrict__ shapes,         // [L, 2] (H, W)
    const int* __restrict__ starts,         // [L]
    const float* __restrict__ pencs,        // [HH, 20, 32]
    unsigned short* __restrict__ wtd) {     // [B*N, 256] bf16
  __shared__ __align__(16) int pbuf[4][20][8];
  const int wv = threadIdx.x >> 6;
  const int lane = threadIdx.x & 63;
  const int beta = blockIdx.x;
  const int sig = (beta & 7) * 2 + (beta >> 12);        // slice 0..15
  const int chunk = (beta >> 3) & 511;                  // 0..511
  const int h = sig & 7;
  const int b = sig >> 3;
  const int bn = b * N_ + chunk * 4 + wv;
  const int j = lane & 31;
  const int half = lane >> 5;

  if (lane < 20) {
    const int pp = lane;
    const int l = pp >> 2;
    const float2 oxy = *(const float2*)(offb + (size_t)bn * 384 + h * 40 + pp * 2);
    const float2 pxy = *(const float2*)(priors + ((size_t)bn * 5 + l) * 2);
    const int Wd = shapes[l * 2 + 1];
    const int Hd = shapes[l * 2 + 0];
    const int st = starts[l];
    const float Wf = (float)Wd, Hf = (float)Hd;
    const float x = (pxy.x + oxy.x / Wf) * Wf - 0.5f;
    const float y = (pxy.y + oxy.y / Hf) * Hf - 0.5f;
    const float x0f = floorf(x), y0f = floorf(y);
    const float fx = x - x0f, fy = y - y0f;
    const int xi = (int)x0f, yi = (int)y0f;
    int a[4]; unsigned wpk[4];
#pragma unroll
    for (int dy = 0; dy < 2; ++dy)
#pragma unroll
      for (int dx = 0; dx < 2; ++dx) {
        const int xc = xi + dx, yc = yi + dy;
        const bool valid = (xc >= 0) & (xc < Wd) & (yc >= 0) & (yc < Hd);
        const float wt = (dx ? fx : 1.f - fx) * (dy ? fy : 1.f - fy);
        const float wm = valid ? wt : 0.f;
        const int xcc = min(max(xc, 0), Wd - 1);
        const int ycc = min(max(yc, 0), Hd - 1);
        a[dy * 2 + dx] = (st + ycc * Wd + xcc) * 32;
        wpk[dy * 2 + dx] = pkrtz_u(wm, wm);  // duplicated half2
      }
    *(int4*)&pbuf[wv][pp][0] = make_int4(a[0], a[1], a[2], a[3]);
    *(int4*)&pbuf[wv][pp][4] =
        make_int4((int)wpk[0], (int)wpk[1], (int)wpk[2], (int)wpk[3]);
  }

  const int jc = j & 15;
  float2 q2 = *(const float2*)(qb + (size_t)bn * 256 + h * DQK + 2 * jc);
  q2.x *= 0.17677669529663687f;
  q2.y *= 0.17677669529663687f;
  const h2 qpk = pkrtz(q2.x, q2.y);
  float qpe[10];
#pragma unroll
  for (int i = 0; i < 10; ++i) {
    const float2 pe = *(const float2*)(
        pencs + ((size_t)h * 20 + 2 * i + half) * DQK + 2 * jc);
    qpe[i] = q2.x * pe.x + q2.y * pe.y;
  }

  const unsigned* kvd = (const unsigned*)(kvt + (size_t)(b * HH + h) * (S_ * 64));

  // 5-deep rotation, all indices compile-time (full unroll) -> stays in regs
  uint4 wwp[5];
  unsigned g[5][4];
#pragma unroll
  for (int i = 0; i < 5; ++i) {
    const int4 aa = *(const int4*)&pbuf[wv][2 * i + half][0];
    wwp[i] = *(const uint4*)&pbuf[wv][2 * i + half][4];
    g[i][0] = kvd[(unsigned)aa.x + j];
    g[i][1] = kvd[(unsigned)aa.y + j];
    g[i][2] = kvd[(unsigned)aa.z + j];
    g[i][3] = kvd[(unsigned)aa.w + j];
  }

  h2 sam[10];
  float lg[10];
#pragma unroll
  for (int i = 0; i < 10; ++i) {
    const int s = i % 5;   // constant after unroll
    const uint4 wt = wwp[s];
    const unsigned g0 = g[s][0], g1 = g[s][1], g2 = g[s][2], g3 = g[s][3];
    if (i < 5) {           // refill slot s with pair i+5
      const int4 aa = *(const int4*)&pbuf[wv][2 * (i + 5) + half][0];
      wwp[s] = *(const uint4*)&pbuf[wv][2 * (i + 5) + half][4];
      g[s][0] = kvd[(unsigned)aa.x + j];
      g[s][1] = kvd[(unsigned)aa.y + j];
      g[s][2] = kvd[(unsigned)aa.z + j];
      g[s][3] = kvd[(unsigned)aa.w + j];
    }
    // packed bilinear: 4x v_pk_fma_f16
    h2 v = u2h(wt.x) * u2h(g0);
    v = u2h(wt.y) * u2h(g1) + v;
    v = u2h(wt.z) * u2h(g2) + v;
    v = u2h(wt.w) * u2h(g3) + v;
    sam[i] = v;
    // logit partial: v_dot2_f32_f16 (f32 accumulate)
    float part = (j < 16) ? __builtin_amdgcn_fdot2(qpk, v, qpe[i], false) : 0.f;
    part = dppadd<0xB1>(part);    // quad_perm xor1
    part = dppadd<0x4E>(part);    // quad_perm xor2
    part = dppadd<0x124>(part);   // row_ror:4
    part = dppadd<0x128>(part);   // row_ror:8 -> row16 sum
    lg[i] = part + __shfl_xor(part, 16, 64);
  }

  float mx = lg[0];
#pragma unroll
  for (int i = 1; i < 10; ++i) mx = fmaxf(mx, lg[i]);
  mx = fmaxf(mx, __shfl_xor(mx, 32, 64));
  float se = 0.f;
#pragma unroll
  for (int i = 0; i < 10; ++i) {
    lg[i] = __expf(lg[i] - mx);
    se += lg[i];
  }
  se += __shfl_xor(se, 32, 64);
  const float inv = 1.f / se;

  float ax = 0.f, ay = 0.f;
#pragma unroll
  for (int i = 0; i < 10; ++i) {
    ax = fmaf(lg[i], (float)sam[i][0], ax);
    ay = fmaf(lg[i], (float)sam[i][1], ay);
  }
  ax += __shfl_xor(ax, 32, 64);
  ay += __shfl_xor(ay, 32, 64);

  if (half == 0 && j >= 16) {
    const unsigned u = (unsigned)f2b(ax * inv) | ((unsigned)f2b(ay * inv) << 16);
    ((unsigned*)wtd)[(size_t)bn * 128 + h * 16 + (j - 16)] = u;
  }
}

// ---------------------------------------------------------------------------
extern "C" void kernel_launch(void* const* d_in, const int* in_sizes, int n_in,
                              void* d_out, int out_size, void* d_ws, size_t ws_size,
                              hipStream_t stream) {
  const float* in_feats = (const float*)d_in[0];
  const float* priors   = (const float*)d_in[1];
  const float* sfeats   = (const float*)d_in[2];
  const int*   shapes   = (const int*)d_in[3];
  const int*   starts   = (const int*)d_in[4];
  const float* W_off    = (const float*)d_in[5];
  const float* b_off    = (const float*)d_in[6];
  const float* W_q      = (const float*)d_in[7];
  const float* b_q      = (const float*)d_in[8];
  const float* W_kv     = (const float*)d_in[9];
  const float* b_kv     = (const float*)d_in[10];
  const float* pencs    = (const float*)d_in[11];
  const float* W_out    = (const float*)d_in[12];
  const float* b_out    = (const float*)d_in[13];
  float* out = (float*)d_out;

  char* w = (char*)d_ws;
  unsigned short* kvt = (unsigned short*)w;            // 44.7 MB (f16)
  w += (size_t)B_ * HH * S_ * 64 * 2;
  unsigned short* sf_bf = (unsigned short*)w;          // 22.3 MB
  w += (size_t)B_ * S_ * 256 * 2;
  unsigned short* if_hi = (unsigned short*)w; w += (size_t)4096 * 256 * 2;
  unsigned short* if_lo = (unsigned short*)w; w += (size_t)4096 * 256 * 2;
  unsigned short* wkv_bf = (unsigned short*)w;  w += (size_t)512 * 256 * 2;
  unsigned short* wq_bf  = (unsigned short*)w;  w += (size_t)256 * 256 * 2;
  unsigned short* wout_bf = (unsigned short*)w; w += (size_t)256 * 256 * 2;
  unsigned short* woff_hi = (unsigned short*)w; w += (size_t)384 * 256 * 2;
  unsigned short* woff_lo = (unsigned short*)w; w += (size_t)384 * 256 * 2;
  float* offb = (float*)w;  w += (size_t)4096 * 384 * 4;
  float* qb   = (float*)w;  w += (size_t)4096 * 256 * 4;
  unsigned short* wtd_bf = (unsigned short*)w; w += (size_t)4096 * 256 * 2;

  // 1) conversions (6704 blocks)
  cvt_all<<<E7 / 256, 256, 0, stream>>>(
      sfeats, in_feats, W_kv, W_q, W_out, W_off,
      sf_bf, if_hi, if_lo, wkv_bf, wq_bf, wout_bf, woff_hi, woff_lo);

  // 2) off + q + kv (kv: BK=32 dbuf, counted vmcnt, f16 swapped-store epilogue)
  ubergemm<<<1536, 256, 0, stream>>>(
      sf_bf, wkv_bf, if_hi, if_lo, woff_hi, woff_lo, wq_bf,
      b_kv, b_off, b_q, kvt, offb, qb);

  // 3) fused prep + sampling + attention (packed-f16 math)
  sample_attn6<<<(B_ * N_ * HH) / 4, 256, 0, stream>>>(
      kvt, offb, qb, priors, shapes, starts, pencs, wtd_bf);

  // 4) out = weighted @ W_out^T + b_out
  gemm_out<<<dim3(2, 32), 256, 0, stream>>>(wtd_bf, wout_bf, b_out, out);
}

// Round 15
// 81.837 us; speedup vs baseline: 1.2505x; 1.0197x over previous
//
#include <hip/hip_runtime.h>
#include <cstddef>

#define B_  2
#define N_  2048
#define L_  5
#define HH  8
#define P_  4
#define S_  21824
#define DQK 32

using bf16x8 = __attribute__((ext_vector_type(8))) short;
using f32x4  = __attribute__((ext_vector_type(4))) float;
using us8    = __attribute__((ext_vector_type(8))) unsigned short;
using h2     = __attribute__((ext_vector_type(2))) _Float16;

__device__ __forceinline__ unsigned short f2b(float f) {
  unsigned u = __builtin_bit_cast(unsigned, f);
  u += 0x7FFFu + ((u >> 16) & 1u);            // round-to-nearest-even
  return (unsigned short)(u >> 16);
}
__device__ __forceinline__ float b2f(unsigned short h) {
  return __builtin_bit_cast(float, ((unsigned)h) << 16);
}
// packed f32x2 -> bf16x2 (RNE): lo -> low16, hi -> high16
__device__ __forceinline__ unsigned cvtpk(float lo, float hi) {
  unsigned r;
  asm("v_cvt_pk_bf16_f32 %0, %1, %2" : "=v"(r) : "v"(lo), "v"(hi));
  return r;
}
// packed f32x2 -> f16x2 (RTZ) with explicit bit_casts (builtin returns __fp16x2)
__device__ __forceinline__ h2 pkrtz(float a, float b) {
  return __builtin_bit_cast(h2, __builtin_amdgcn_cvt_pkrtz(a, b));
}
__device__ __forceinline__ unsigned pkrtz_u(float a, float b) {
  return __builtin_bit_cast(unsigned, __builtin_amdgcn_cvt_pkrtz(a, b));
}
__device__ __forceinline__ h2 u2h(unsigned u) { return __builtin_bit_cast(h2, u); }

__device__ __forceinline__ void gld_lds16(const void* g, void* l) {
  __builtin_amdgcn_global_load_lds(
      (const __attribute__((address_space(1))) unsigned int*)g,
      (__attribute__((address_space(3))) unsigned int*)l, 16, 0, 0);
}

// DPP-based add: v += permuted(v). VALU pipe, no LDS round-trip.
template <int CTRL>
__device__ __forceinline__ float dppadd(float v) {
  const int x = __builtin_bit_cast(int, v);
  return v + __builtin_bit_cast(float,
      __builtin_amdgcn_update_dpp(x, x, CTRL, 0xF, 0xF, false));
}

// ---------------------------------------------------------------------------
// cvt_all: small tensors only (sfeats is consumed as f32 by the kv GEMM).
// ---------------------------------------------------------------------------
#define F0 131072   // in_feats -> if_hi + if_lo   (4096*256/8)
#define F1 147456   // + W_kv -> wkv_bf            (512*256/8)
#define F2 155648   // + W_q  -> wq_bf             (256*256/8)
#define F3 163840   // + W_out -> wout_bf          (256*256/8)
#define F4 176128   // + W_off(pad384) -> woff_hi  (384*256/8)
#define F5 188416   // + W_off(pad384) -> woff_lo  (384*256/8)

__device__ __forceinline__ void cvt8_plain(const float* s, unsigned short* d, int u) {
  const float4 a = ((const float4*)s)[2 * u];
  const float4 b = ((const float4*)s)[2 * u + 1];
  us8 o;
  o[0] = f2b(a.x); o[1] = f2b(a.y); o[2] = f2b(a.z); o[3] = f2b(a.w);
  o[4] = f2b(b.x); o[5] = f2b(b.y); o[6] = f2b(b.z); o[7] = f2b(b.w);
  ((us8*)d)[u] = o;
}
__device__ __forceinline__ unsigned short f2b_lo(float x) {
  return f2b(x - b2f(f2b(x)));
}
__device__ __forceinline__ void cvt8_lo(const float* s, unsigned short* d, int u) {
  const float4 a = ((const float4*)s)[2 * u];
  const float4 b = ((const float4*)s)[2 * u + 1];
  us8 o;
  o[0] = f2b_lo(a.x); o[1] = f2b_lo(a.y); o[2] = f2b_lo(a.z); o[3] = f2b_lo(a.w);
  o[4] = f2b_lo(b.x); o[5] = f2b_lo(b.y); o[6] = f2b_lo(b.z); o[7] = f2b_lo(b.w);
  ((us8*)d)[u] = o;
}
__device__ __forceinline__ void cvt8_both(const float* s, unsigned short* dh,
                                          unsigned short* dl, int u) {
  const float4 a = ((const float4*)s)[2 * u];
  const float4 b = ((const float4*)s)[2 * u + 1];
  us8 oh, ol;
  const float v[8] = {a.x, a.y, a.z, a.w, b.x, b.y, b.z, b.w};
#pragma unroll
  for (int k = 0; k < 8; ++k) {
    const unsigned short hh = f2b(v[k]);
    oh[k] = hh;
    ol[k] = f2b(v[k] - b2f(hh));
  }
  ((us8*)dh)[u] = oh;
  ((us8*)dl)[u] = ol;
}

__global__ __launch_bounds__(256) void cvt_all(
    const float* __restrict__ in_feats, const float* __restrict__ W_kv,
    const float* __restrict__ W_q, const float* __restrict__ W_out,
    const float* __restrict__ W_off,
    unsigned short* __restrict__ if_hi, unsigned short* __restrict__ if_lo,
    unsigned short* __restrict__ wkv_bf, unsigned short* __restrict__ wq_bf,
    unsigned short* __restrict__ wout_bf, unsigned short* __restrict__ woff_hi,
    unsigned short* __restrict__ woff_lo) {
  const int i = blockIdx.x * 256 + threadIdx.x;
  if      (i < F0) cvt8_both(in_feats, if_hi, if_lo, i);
  else if (i < F1) cvt8_plain(W_kv, wkv_bf, i - F0);
  else if (i < F2) cvt8_plain(W_q, wq_bf, i - F1);
  else if (i < F3) cvt8_plain(W_out, wout_bf, i - F2);
  else if (i < F4) {
    const int u = i - F3;
    if ((u >> 5) < 320) cvt8_plain(W_off, woff_hi, u);
    else ((us8*)woff_hi)[u] = (us8)0;
  } else {
    const int u = i - F4;
    if ((u >> 5) < 320) cvt8_lo(W_off, woff_lo, u);
    else ((us8*)woff_lo)[u] = (us8)0;
  }
}

// ---------------------------------------------------------------------------
// Classic staged MFMA tile (128x128, BK=64) for off/q/out (proven body).
// ---------------------------------------------------------------------------
__device__ __forceinline__ void mfma_compute(
    const unsigned short* As, const unsigned short* Bs,
    int wr, int wc, int fr, int fq, f32x4 (&acc)[4][4]) {
#pragma unroll
  for (int kk = 0; kk < 2; ++kk) {
    bf16x8 af[4], bfv[4];
#pragma unroll
    for (int i = 0; i < 4; ++i) {
      const int ar = wr * 64 + i * 16 + fr;
      const int cha = (kk * 4 + fq) ^ (ar & 7);
      af[i] = *(const bf16x8*)(As + ar * 64 + cha * 8);
      const int br = wc * 64 + i * 16 + fr;
      const int chb = (kk * 4 + fq) ^ (br & 7);
      bfv[i] = *(const bf16x8*)(Bs + br * 64 + chb * 8);
    }
#pragma unroll
    for (int i = 0; i < 4; ++i)
#pragma unroll
      for (int j = 0; j < 4; ++j)
        acc[i][j] = __builtin_amdgcn_mfma_f32_16x16x32_bf16(
            af[i], bfv[j], acc[i][j], 0, 0, 0);
  }
}

__device__ __forceinline__ void mfma_tile_bf16(
    const unsigned short* __restrict__ Ap, const unsigned short* __restrict__ Wp,
    unsigned short* As, unsigned short* Bs,
    int row0, int col0, int wv, int wr, int wc, int fr, int fq,
    int srow, int sch, f32x4 (&acc)[4][4]) {
  for (int k0 = 0; k0 < 256; k0 += 64) {
#pragma unroll
    for (int i = 0; i < 4; ++i) {
      const int r = i * 32 + srow;
      const int ca = sch ^ (r & 7);
      gld_lds16(Ap + (size_t)(row0 + r) * 256 + k0 + ca * 8,
                As + (size_t)(i * 32 + wv * 8) * 64);
      gld_lds16(Wp + (size_t)(col0 + r) * 256 + k0 + ca * 8,
                Bs + (size_t)(i * 32 + wv * 8) * 64);
    }
    __syncthreads();
    mfma_compute(As, Bs, wr, wc, fr, fq, acc);
    __syncthreads();
  }
}

// ---------------------------------------------------------------------------
// Ubergemm: off [0,96) | q [96,160) | kv [160,1536).
// kv path: A staged as RAW F32 via global_load_lds (4 chunks/thread,
// inverse-swizzled source), BK=32 double-buffered, counted vmcnt(6);
// f32->bf16 conversion happens IN REGISTERS between ds_read_b128 and MFMA
// (identical RNE rounding to the old cvt pass). B stays bf16. kvt stored f16.
// LDS: A 2x16KB + B 2x8KB = 48KB.
// ---------------------------------------------------------------------------
__global__ __launch_bounds__(256) void ubergemm(
    const float* __restrict__ sfeats,
    const unsigned short* __restrict__ wkv_bf,
    const unsigned short* __restrict__ if_hi,
    const unsigned short* __restrict__ if_lo,
    const unsigned short* __restrict__ woff_hi,
    const unsigned short* __restrict__ woff_lo,
    const unsigned short* __restrict__ wq_bf,
    const float* __restrict__ b_kv, const float* __restrict__ b_off,
    const float* __restrict__ b_q,
    unsigned short* __restrict__ kvt, float* __restrict__ offb,
    float* __restrict__ qb) {
  __shared__ __align__(16) unsigned char ldsraw[49152];   // 48 KB

  const int tid = threadIdx.x;
  const int lane = tid & 63;
  const int wv = tid >> 6;
  const int wr = wv >> 1, wc = wv & 1;
  const int fr = lane & 15, fq = lane >> 4;
  const int bx = blockIdx.x;

  f32x4 acc[4][4] = {};

  if (bx >= 160) {          // ---- kv path ----
    const int t = bx - 160;
    const int x = t & 7;
    const int idx = t >> 3;
    const int c = idx & 3;
    const int g = (idx >> 2) * 8 + x;
    if (g >= 341) return;
    const int row0 = g * 128;
    const int col0 = c * 128;

    // A buffers: f32 [128][32] = 16 KB each; B buffers: bf16 [128][32] = 8 KB
    float* Afb[2] = {(float*)ldsraw, (float*)(ldsraw + 16384)};
    unsigned short* Bb[2] = {(unsigned short*)(ldsraw + 32768),
                             (unsigned short*)(ldsraw + 40960)};

    // stage: 4 A-chunks (f32) + 2 B-chunks (bf16) per thread = 6 vmem ops
#define KV_STAGE(KK, BUF)                                                     \
    {                                                                         \
      _Pragma("unroll")                                                       \
      for (int ld = 0; ld < 4; ++ld) {   /* A: 1024 chunks of 16B */          \
        const int ci = ld * 256 + tid;                                        \
        const int rw = ci >> 3, cc = ci & 7;                                  \
        const int ca = cc ^ (rw & 7);                                         \
        gld_lds16(sfeats + (size_t)(row0 + rw) * 256 + (KK) * 32 + ca * 4,    \
                  (char*)Afb[BUF] + (ld * 4096 + wv * 1024));                 \
      }                                                                       \
      _Pragma("unroll")                                                       \
      for (int ld = 0; ld < 2; ++ld) {   /* B: 512 chunks of 16B */           \
        const int ci = ld * 256 + tid;                                        \
        const int rw = ci >> 2, cc = ci & 3;                                  \
        const int ca = cc ^ (rw & 3);                                         \
        gld_lds16(wkv_bf + (size_t)(col0 + rw) * 256 + (KK) * 32 + ca * 8,    \
                  (char*)Bb[BUF] + (ld * 4096 + wv * 1024));                  \
      }                                                                       \
    }

    KV_STAGE(0, 0);
#pragma unroll
    for (int k = 0; k < 8; ++k) {
      if (k < 7) {
        KV_STAGE(k + 1, (k + 1) & 1);
        asm volatile("s_waitcnt vmcnt(6)" ::: "memory");
      } else {
        asm volatile("s_waitcnt vmcnt(0)" ::: "memory");
      }
      __builtin_amdgcn_s_barrier();
      __builtin_amdgcn_sched_barrier(0);
      const float* Ac = Afb[k & 1];
      const unsigned short* Bc = Bb[k & 1];
      bf16x8 af[4], bfv[4];
#pragma unroll
      for (int i = 0; i < 4; ++i) {
        const int ar = wr * 64 + i * 16 + fr;
        const int swz = ar & 7;
        // row = 32 floats; chunk = 4 floats; lane reads chunks fq*2, fq*2+1
        const float4 a0 = *(const float4*)(Ac + ar * 32 + (((fq * 2) ^ swz) * 4));
        const float4 a1 = *(const float4*)(Ac + ar * 32 + (((fq * 2 + 1) ^ swz) * 4));
        uint4 u;
        u.x = cvtpk(a0.x, a0.y);
        u.y = cvtpk(a0.z, a0.w);
        u.z = cvtpk(a1.x, a1.y);
        u.w = cvtpk(a1.z, a1.w);
        af[i] = __builtin_bit_cast(bf16x8, u);
      }
#pragma unroll
      for (int j = 0; j < 4; ++j) {
        const int nr = wc * 64 + j * 16 + fr;
        bfv[j] = *(const bf16x8*)(Bc + (nr * 4 + (fq ^ (nr & 3))) * 8);
      }
#pragma unroll
      for (int j = 0; j < 4; ++j)
#pragma unroll
        for (int i = 0; i < 4; ++i)
          acc[j][i] = __builtin_amdgcn_mfma_f32_16x16x32_bf16(
              bfv[j], af[i], acc[j][i], 0, 0, 0);   // swapped: C^T fragments
      __builtin_amdgcn_s_barrier();
    }
#undef KV_STAGE

    // epilogue: lane holds 4 consecutive channels per tile -> f16 dword stores
#pragma unroll
    for (int j = 0; j < 4; ++j) {
      const int c0 = col0 + wc * 64 + j * 16 + fq * 4;
      const float4 bb = *(const float4*)(b_kv + c0);
      const int h = c0 >> 6;
      const int cc = c0 & 63;
#pragma unroll
      for (int i = 0; i < 4; ++i) {
        const int sl = row0 + wr * 64 + i * 16 + fr;
        const int b = (sl >= S_) ? 1 : 0;
        const int s = sl - b * S_;
        unsigned* dst = (unsigned*)(kvt + ((size_t)(b * HH + h) * S_ + s) * 64 + cc);
        dst[0] = pkrtz_u(acc[j][i][0] + bb.x, acc[j][i][1] + bb.y);
        dst[1] = pkrtz_u(acc[j][i][2] + bb.z, acc[j][i][3] + bb.w);
      }
    }
    return;
  }

  // ---- off / q paths (classic staged tiles, first 32 KB of LDS) ----
  unsigned short* As = (unsigned short*)ldsraw;
  unsigned short* Bs = (unsigned short*)(ldsraw + 16384);
  const int srow = tid >> 3;
  const int sch = tid & 7;
  int row0, col0, ldc, nbias;
  const float* bias;
  float* Cf;
  if (bx < 96) {            // off: 3 K-segments, bf16x3
    col0 = (bx % 3) * 128; row0 = (bx / 3) * 128;
    bias = b_off; Cf = offb; ldc = 384; nbias = 320;
    mfma_tile_bf16(if_hi, woff_hi, As, Bs, row0, col0, wv, wr, wc, fr, fq, srow, sch, acc);
    mfma_tile_bf16(if_hi, woff_lo, As, Bs, row0, col0, wv, wr, wc, fr, fq, srow, sch, acc);
    mfma_tile_bf16(if_lo, woff_hi, As, Bs, row0, col0, wv, wr, wc, fr, fq, srow, sch, acc);
  } else {                  // q
    const int t = bx - 96;
    col0 = (t & 1) * 128; row0 = (t >> 1) * 128;
    bias = b_q; Cf = qb; ldc = 256; nbias = 256;
    mfma_tile_bf16(if_hi, wq_bf, As, Bs, row0, col0, wv, wr, wc, fr, fq, srow, sch, acc);
  }

#pragma unroll
  for (int j = 0; j < 4; ++j) {
    const int n = col0 + wc * 64 + j * 16 + fr;
    const float bv = (n < nbias) ? bias[n] : 0.f;
#pragma unroll
    for (int i = 0; i < 4; ++i) {
      const int mbase = row0 + wr * 64 + i * 16 + fq * 4;
#pragma unroll
      for (int r = 0; r < 4; ++r)
        Cf[(size_t)(mbase + r) * ldc + n] = acc[i][j][r] + bv;
    }
  }
}

// ---------------------------------------------------------------------------
// out-projection GEMM: bf16 MFMA, f32 out.
// ---------------------------------------------------------------------------
__global__ __launch_bounds__(256) void gemm_out(
    const unsigned short* __restrict__ A, const unsigned short* __restrict__ Wt,
    const float* __restrict__ bias, float* __restrict__ C) {
  __shared__ __align__(16) unsigned short As[128 * 64];
  __shared__ __align__(16) unsigned short Bs[128 * 64];
  const int tid = threadIdx.x;
  const int lane = tid & 63;
  const int wv = tid >> 6;
  const int wr = wv >> 1, wc = wv & 1;
  const int fr = lane & 15, fq = lane >> 4;
  const int row0 = blockIdx.y * 128, col0 = blockIdx.x * 128;
  const int srow = tid >> 3, sch = tid & 7;
  f32x4 acc[4][4] = {};
  mfma_tile_bf16(A, Wt, As, Bs, row0, col0, wv, wr, wc, fr, fq, srow, sch, acc);
#pragma unroll
  for (int j = 0; j < 4; ++j) {
    const int n = col0 + wc * 64 + j * 16 + fr;
    const float bv = bias[n];
#pragma unroll
    for (int i = 0; i < 4; ++i) {
      const int mbase = row0 + wr * 64 + i * 16 + fq * 4;
#pragma unroll
      for (int r = 0; r < 4; ++r)
        C[(size_t)(mbase + r) * 256 + n] = acc[i][j][r] + bv;
    }
  }
}

// ---------------------------------------------------------------------------
// sample_attn6: packed-f16 math. kvt is f16; bilinear = v_pk_fma_f16;
// logit = v_dot2_f32_f16. Slice-phased XCD decode + 5-deep gather prefetch.
// ---------------------------------------------------------------------------
__global__ __launch_bounds__(256) void sample_attn6(
    const unsigned short* __restrict__ kvt, // [B*HH, S, 64] f16
    const float* __restrict__ offb,         // [B*N, 384]
    const float* __restrict__ qb,           // [B*N, 256]
    const float* __restrict__ priors,       // [B, N, L, 2]
    const int* __restrict__ shapes,         // [L, 2] (H, W)
    const int* __restrict__ starts,         // [L]
    const float* __restrict__ pencs,        // [HH, 20, 32]
    unsigned short* __restrict__ wtd) {     // [B*N, 256] bf16
  __shared__ __align__(16) int pbuf[4][20][8];
  const int wv = threadIdx.x >> 6;
  const int lane = threadIdx.x & 63;
  const int beta = blockIdx.x;
  const int sig = (beta & 7) * 2 + (beta >> 12);        // slice 0..15
  const int chunk = (beta >> 3) & 511;                  // 0..511
  const int h = sig & 7;
  const int b = sig >> 3;
  const int bn = b * N_ + chunk * 4 + wv;
  const int j = lane & 31;
  const int half = lane >> 5;

  if (lane < 20) {
    const int pp = lane;
    const int l = pp >> 2;
    const float2 oxy = *(const float2*)(offb + (size_t)bn * 384 + h * 40 + pp * 2);
    const float2 pxy = *(const float2*)(priors + ((size_t)bn * 5 + l) * 2);
    const int Wd = shapes[l * 2 + 1];
    const int Hd = shapes[l * 2 + 0];
    const int st = starts[l];
    const float Wf = (float)Wd, Hf = (float)Hd;
    const float x = (pxy.x + oxy.x / Wf) * Wf - 0.5f;
    const float y = (pxy.y + oxy.y / Hf) * Hf - 0.5f;
    const float x0f = floorf(x), y0f = floorf(y);
    const float fx = x - x0f, fy = y - y0f;
    const int xi = (int)x0f, yi = (int)y0f;
    int a[4]; unsigned wpk[4];
#pragma unroll
    for (int dy = 0; dy < 2; ++dy)
#pragma unroll
      for (int dx = 0; dx < 2; ++dx) {
        const int xc = xi + dx, yc = yi + dy;
        const bool valid = (xc >= 0) & (xc < Wd) & (yc >= 0) & (yc < Hd);
        const float wt = (dx ? fx : 1.f - fx) * (dy ? fy : 1.f - fy);
        const float wm = valid ? wt : 0.f;
        const int xcc = min(max(xc, 0), Wd - 1);
        const int ycc = min(max(yc, 0), Hd - 1);
        a[dy * 2 + dx] = (st + ycc * Wd + xcc) * 32;
        wpk[dy * 2 + dx] = pkrtz_u(wm, wm);  // duplicated half2
      }
    *(int4*)&pbuf[wv][pp][0] = make_int4(a[0], a[1], a[2], a[3]);
    *(int4*)&pbuf[wv][pp][4] =
        make_int4((int)wpk[0], (int)wpk[1], (int)wpk[2], (int)wpk[3]);
  }

  const int jc = j & 15;
  float2 q2 = *(const float2*)(qb + (size_t)bn * 256 + h * DQK + 2 * jc);
  q2.x *= 0.17677669529663687f;
  q2.y *= 0.17677669529663687f;
  const h2 qpk = pkrtz(q2.x, q2.y);
  float qpe[10];
#pragma unroll
  for (int i = 0; i < 10; ++i) {
    const float2 pe = *(const float2*)(
        pencs + ((size_t)h * 20 + 2 * i + half) * DQK + 2 * jc);
    qpe[i] = q2.x * pe.x + q2.y * pe.y;
  }

  const unsigned* kvd = (const unsigned*)(kvt + (size_t)(b * HH + h) * (S_ * 64));

  uint4 wwp[5];
  unsigned g[5][4];
#pragma unroll
  for (int i = 0; i < 5; ++i) {
    const int4 aa = *(const int4*)&pbuf[wv][2 * i + half][0];
    wwp[i] = *(const uint4*)&pbuf[wv][2 * i + half][4];
    g[i][0] = kvd[(unsigned)aa.x + j];
    g[i][1] = kvd[(unsigned)aa.y + j];
    g[i][2] = kvd[(unsigned)aa.z + j];
    g[i][3] = kvd[(unsigned)aa.w + j];
  }

  h2 sam[10];
  float lg[10];
#pragma unroll
  for (int i = 0; i < 10; ++i) {
    const int s = i % 5;   // constant after unroll
    const uint4 wt = wwp[s];
    const unsigned g0 = g[s][0], g1 = g[s][1], g2 = g[s][2], g3 = g[s][3];
    if (i < 5) {           // refill slot s with pair i+5
      const int4 aa = *(const int4*)&pbuf[wv][2 * (i + 5) + half][0];
      wwp[s] = *(const uint4*)&pbuf[wv][2 * (i + 5) + half][4];
      g[s][0] = kvd[(unsigned)aa.x + j];
      g[s][1] = kvd[(unsigned)aa.y + j];
      g[s][2] = kvd[(unsigned)aa.z + j];
      g[s][3] = kvd[(unsigned)aa.w + j];
    }
    // packed bilinear: 4x v_pk_fma_f16
    h2 v = u2h(wt.x) * u2h(g0);
    v = u2h(wt.y) * u2h(g1) + v;
    v = u2h(wt.z) * u2h(g2) + v;
    v = u2h(wt.w) * u2h(g3) + v;
    sam[i] = v;
    // logit partial: v_dot2_f32_f16 (f32 accumulate)
    float part = (j < 16) ? __builtin_amdgcn_fdot2(qpk, v, qpe[i], false) : 0.f;
    part = dppadd<0xB1>(part);    // quad_perm xor1
    part = dppadd<0x4E>(part);    // quad_perm xor2
    part = dppadd<0x124>(part);   // row_ror:4
    part = dppadd<0x128>(part);   // row_ror:8 -> row16 sum
    lg[i] = part + __shfl_xor(part, 16, 64);
  }

  float mx = lg[0];
#pragma unroll
  for (int i = 1; i < 10; ++i) mx = fmaxf(mx, lg[i]);
  mx = fmaxf(mx, __shfl_xor(mx, 32, 64));
  float se = 0.f;
#pragma unroll
  for (int i = 0; i < 10; ++i) {
    lg[i] = __expf(lg[i] - mx);
    se += lg[i];
  }
  se += __shfl_xor(se, 32, 64);
  const float inv = 1.f / se;

  float ax = 0.f, ay = 0.f;
#pragma unroll
  for (int i = 0; i < 10; ++i) {
    ax = fmaf(lg[i], (float)sam[i][0], ax);
    ay = fmaf(lg[i], (float)sam[i][1], ay);
  }
  ax += __shfl_xor(ax, 32, 64);
  ay += __shfl_xor(ay, 32, 64);

  if (half == 0 && j >= 16) {
    const unsigned u = (unsigned)f2b(ax * inv) | ((unsigned)f2b(ay * inv) << 16);
    ((unsigned*)wtd)[(size_t)bn * 128 + h * 16 + (j - 16)] = u;
  }
}

// ---------------------------------------------------------------------------
extern "C" void kernel_launch(void* const* d_in, const int* in_sizes, int n_in,
                              void* d_out, int out_size, void* d_ws, size_t ws_size,
                              hipStream_t stream) {
  const float* in_feats = (const float*)d_in[0];
  const float* priors   = (const float*)d_in[1];
  const float* sfeats   = (const float*)d_in[2];
  const int*   shapes   = (const int*)d_in[3];
  const int*   starts   = (const int*)d_in[4];
  const float* W_off    = (const float*)d_in[5];
  const float* b_off    = (const float*)d_in[6];
  const float* W_q      = (const float*)d_in[7];
  const float* b_q      = (const float*)d_in[8];
  const float* W_kv     = (const float*)d_in[9];
  const float* b_kv     = (const float*)d_in[10];
  const float* pencs    = (const float*)d_in[11];
  const float* W_out    = (const float*)d_in[12];
  const float* b_out    = (const float*)d_in[13];
  float* out = (float*)d_out;

  char* w = (char*)d_ws;
  unsigned short* kvt = (unsigned short*)w;            // 44.7 MB (f16)
  w += (size_t)B_ * HH * S_ * 64 * 2;
  unsigned short* if_hi = (unsigned short*)w; w += (size_t)4096 * 256 * 2;
  unsigned short* if_lo = (unsigned short*)w; w += (size_t)4096 * 256 * 2;
  unsigned short* wkv_bf = (unsigned short*)w;  w += (size_t)512 * 256 * 2;
  unsigned short* wq_bf  = (unsigned short*)w;  w += (size_t)256 * 256 * 2;
  unsigned short* wout_bf = (unsigned short*)w; w += (size_t)256 * 256 * 2;
  unsigned short* woff_hi = (unsigned short*)w; w += (size_t)384 * 256 * 2;
  unsigned short* woff_lo = (unsigned short*)w; w += (size_t)384 * 256 * 2;
  float* offb = (float*)w;  w += (size_t)4096 * 384 * 4;
  float* qb   = (float*)w;  w += (size_t)4096 * 256 * 4;
  unsigned short* wtd_bf = (unsigned short*)w; w += (size_t)4096 * 256 * 2;

  // 1) small conversions only (736 blocks)
  cvt_all<<<F5 / 256, 256, 0, stream>>>(
      in_feats, W_kv, W_q, W_out, W_off,
      if_hi, if_lo, wkv_bf, wq_bf, wout_bf, woff_hi, woff_lo);

  // 2) off + q + kv (kv: f32-A async staging + reg-cvt, counted vmcnt(6))
  ubergemm<<<1536, 256, 0, stream>>>(
      sfeats, wkv_bf, if_hi, if_lo, woff_hi, woff_lo, wq_bf,
      b_kv, b_off, b_q, kvt, offb, qb);

  // 3) fused prep + sampling + attention (packed-f16 math)
  sample_attn6<<<(B_ * N_ * HH) / 4, 256, 0, stream>>>(
      kvt, offb, qb, priors, shapes, starts, pencs, wtd_bf);

  // 4) out = weighted @ W_out^T + b_out
  gemm_out<<<dim3(2, 32), 256, 0, stream>>>(wtd_bf, wout_bf, b_out, out);
}